// Round 15
// baseline (108.033 us; speedup 1.0000x reference)
//
#include <hip/hip_runtime.h>
#include <hip/hip_bf16.h>

#define HEADS 8
#define DIM_HEAD 32
#define GROUPS 8
#define CCH 256            // channels
#define NTOK 4096          // d*h*w = 16^3
#define EPS 1e-5f
#define GN_SPLIT 32
#define JS 4               // attention j-split (R14 lesson: JS=2 cost occupancy 44->30%)

typedef _Float16 half8 __attribute__((ext_vector_type(8)));
typedef float f32x4 __attribute__((ext_vector_type(4)));

// -------------------- 1. GroupNorm partial stats --------------------
__global__ void gn_stats_partial(const float* __restrict__ x, float* __restrict__ part) {
    const int g  = blockIdx.y;
    const int sp = blockIdx.x;
    const int M = (CCH / GROUPS) * NTOK;        // 131072 contiguous floats per group
    const int chunk = M / GN_SPLIT;             // 4096
    const float4* p = (const float4*)(x + (size_t)g * M + (size_t)sp * chunk);
    float s = 0.f, ss = 0.f;
    for (int i = threadIdx.x; i < chunk / 4; i += blockDim.x) {
        float4 v = p[i];
        s  += v.x + v.y + v.z + v.w;
        ss += v.x*v.x + v.y*v.y + v.z*v.z + v.w*v.w;
    }
    #pragma unroll
    for (int off = 32; off; off >>= 1) {
        s  += __shfl_down(s,  off);
        ss += __shfl_down(ss, off);
    }
    __shared__ float sh0[8], sh1[8];
    const int wave = threadIdx.x >> 6, lane = threadIdx.x & 63;
    if (lane == 0) { sh0[wave] = s; sh1[wave] = ss; }
    __syncthreads();
    if (threadIdx.x == 0) {
        float S = 0.f, SS = 0.f;
        const int nw = blockDim.x >> 6;
        for (int w = 0; w < nw; ++w) { S += sh0[w]; SS += sh1[w]; }
        part[(g * GN_SPLIT + sp) * 2]     = S;
        part[(g * GN_SPLIT + sp) * 2 + 1] = SS;
    }
}

// -------------------- 2. Fold GN into QKV weights + w_out fp16 + x transpose ----
// Blocks 0..767: w2h = fp16(w*gamma*rstd), b2 = b + sum_c w*shift.
// Blocks 768..1023: wouth rows.
// Blocks 1024..1279: x -> fp16 xT[j][c] 64x64 tiles (merged launch).
__global__ __launch_bounds__(256)
void fold_qkv(const float* __restrict__ w, const float* __restrict__ b,
              const float* __restrict__ gamma, const float* __restrict__ beta,
              const float* __restrict__ part, const float* __restrict__ w_out,
              const float* __restrict__ x,
              _Float16* __restrict__ w2h, float* __restrict__ b2,
              _Float16* __restrict__ wouth, _Float16* __restrict__ xT) {
    const int o = blockIdx.x;
    const int c = threadIdx.x;          // 0..255
    if (o >= 4 * CCH) {                 // ---- transpose tile ----
        const int t  = o - 4 * CCH;     // 0..255
        const int jb = (t & 63) * 64;
        const int cb = (t >> 6) * 64;
        __shared__ float tile[64][65];
        const int tj = threadIdx.x & 63, tc = threadIdx.x >> 6;
        #pragma unroll
        for (int cc = 0; cc < 64; cc += 4)
            tile[cc + tc][tj] = x[(size_t)(cb + cc + tc) * NTOK + jb + tj];
        __syncthreads();
        const int wc = threadIdx.x & 63, wj = threadIdx.x >> 6;
        #pragma unroll
        for (int jj = 0; jj < 64; jj += 4)
            xT[(size_t)(jb + jj + wj) * CCH + cb + wc] = (_Float16)tile[wc][jj + wj];
        return;
    }
    if (o >= 3 * CCH) {                 // ---- w_out convert ----
        const int oo = o - 3 * CCH;
        wouth[(size_t)oo * CCH + c] = (_Float16)w_out[(size_t)oo * CCH + c];
        return;
    }
    __shared__ float smean[GROUPS], srstd[GROUPS];
    if (c < GROUPS) {
        float s = 0.f, ss = 0.f;
        #pragma unroll
        for (int i = 0; i < GN_SPLIT; ++i) {
            s  += part[(c * GN_SPLIT + i) * 2];
            ss += part[(c * GN_SPLIT + i) * 2 + 1];
        }
        const float M = (float)((CCH / GROUPS) * NTOK);
        const float mean = s / M;
        const float var  = ss / M - mean * mean;
        smean[c] = mean;
        srstd[c] = rsqrtf(var + EPS);
    }
    __syncthreads();
    const int g = c >> 5;
    const float sc = gamma[c] * srstd[g];
    const float sh = beta[c] - smean[g] * sc;
    const float wv = w[(size_t)o * CCH + c];
    w2h[(size_t)o * CCH + c] = (_Float16)(wv * sc);
    float t = wv * sh;
    #pragma unroll
    for (int off = 32; off; off >>= 1) t += __shfl_down(t, off);
    __shared__ float shred[4];
    const int wave = threadIdx.x >> 6, lane = threadIdx.x & 63;
    if (lane == 0) shred[wave] = t;
    __syncthreads();
    if (threadIdx.x == 0)
        b2[o] = b[o] + shred[0] + shred[1] + shred[2] + shred[3];
}

// -------------------- 3. QKV GEMM via MFMA ------------------------------------
// Q scale folds BOTH 32^-0.5 and log2(e): softmax runs in exp2 domain.
__global__ __launch_bounds__(256)
void qkv_mfma(const _Float16* __restrict__ w2h, const float* __restrict__ b2,
              const _Float16* __restrict__ xT,
              _Float16* __restrict__ q_h, _Float16* __restrict__ k_h,
              _Float16* __restrict__ vT_h) {
    const int tid = threadIdx.x, w = tid >> 6, lane = tid & 63;
    const int la = lane & 15, lg = lane >> 4;
    const int jb = blockIdx.x * 64 + w * 16;   // wave's 16 tokens
    const int ob = blockIdx.y * 16;            // 16 output rows
    const int part = ob >> 8;
    f32x4 acc = {0.f, 0.f, 0.f, 0.f};
    if (part < 2) {
        // A = xT token rows (D row = j), B = w2h o-rows (D col = o)
        const _Float16* arow = xT  + (size_t)(jb + la) * CCH;
        const _Float16* brow = w2h + (size_t)(ob + la) * CCH;
        #pragma unroll
        for (int kk = 0; kk < CCH; kk += 32) {
            const half8 a = *(const half8*)(arow + kk + lg * 8);
            const half8 b = *(const half8*)(brow + kk + lg * 8);
            acc = __builtin_amdgcn_mfma_f32_16x16x32_f16(a, b, acc, 0, 0, 0);
        }
        const int h = (ob & 255) >> 5, dbase = ob & 31;
        const float bias = b2[ob + la];
        _Float16* dst = (part == 0) ? q_h : k_h;
        const float scl = (part == 0) ? 0.25503486f : 1.0f;  // 32^-0.5 * log2(e)
        #pragma unroll
        for (int r = 0; r < 4; ++r) {
            const int j = jb + lg * 4 + r;
            dst[((size_t)h * NTOK + j) * DIM_HEAD + dbase + la] =
                (_Float16)((acc[r] + bias) * scl);
        }
    } else {
        // A = w2h o-rows (D row = o=d), B = xT token rows (D col = j)
        const _Float16* arow = w2h + (size_t)(ob + la) * CCH;
        const _Float16* brow = xT  + (size_t)(jb + la) * CCH;
        #pragma unroll
        for (int kk = 0; kk < CCH; kk += 32) {
            const half8 a = *(const half8*)(arow + kk + lg * 8);
            const half8 b = *(const half8*)(brow + kk + lg * 8);
            acc = __builtin_amdgcn_mfma_f32_16x16x32_f16(a, b, acc, 0, 0, 0);
        }
        const int h = (ob & 255) >> 5, dbase = ob & 31;
        const float4 b4 = *(const float4*)(b2 + ob + lg * 4);
        const float bb[4] = {b4.x, b4.y, b4.z, b4.w};
        #pragma unroll
        for (int r = 0; r < 4; ++r) {
            const int d = dbase + lg * 4 + r;
            vT_h[((size_t)h * DIM_HEAD + d) * NTOK + jb + la] = (_Float16)(acc[r] + bb[r]);
        }
    }
}

// -------------------- 4. Flash attention partial (exp2 + defer, JS=4) ---------
#define TJ 64
#define VPAD 72
__global__ __launch_bounds__(256)
void attn_mfma(const _Float16* __restrict__ q_h, const _Float16* __restrict__ k_h,
               const _Float16* __restrict__ vT_h,
               float* __restrict__ pm, float* __restrict__ pl,
               float* __restrict__ pacc) {
    const int tid = threadIdx.x;
    const int w = tid >> 6, lane = tid & 63;
    const int la = lane & 15, lg = lane >> 4;
    const int h = blockIdx.y;
    const int s = blockIdx.z;
    const int qbase = blockIdx.x * 64 + w * 16;
    const int jlen = NTOK / JS;          // 1024
    const int j0 = s * jlen;

    __shared__ _Float16 lk [2][TJ * DIM_HEAD];
    __shared__ _Float16 lvt[2][DIM_HEAD * VPAD];
    __shared__ __align__(16) _Float16 plds[4][16 * 64];

    const half8 aq = *(const half8*)(q_h + ((size_t)h * NTOK + qbase + la) * DIM_HEAD + lg * 8);

    f32x4 acc0 = {0.f, 0.f, 0.f, 0.f};
    f32x4 acc1 = {0.f, 0.f, 0.f, 0.f};
    float m = -1e30f, l = 0.f;           // per-lane: query la (log2 domain)

    const _Float16* kg = k_h  + (size_t)h * NTOK * DIM_HEAD + (size_t)j0 * DIM_HEAD;
    const _Float16* vg = vT_h + (size_t)h * DIM_HEAD * NTOK + j0;
    const int vrow = tid >> 3, vseg = tid & 7;
    char* pw = (char*)&plds[w][0];

    uint4 kreg, vreg;
    kreg = ((const uint4*)kg)[tid];
    vreg = *(const uint4*)(vg + (size_t)vrow * NTOK + vseg * 8);
    ((uint4*)lk[0])[tid] = kreg;
    *(uint4*)&lvt[0][vrow * VPAD + vseg * 8] = vreg;
    kreg = ((const uint4*)(kg + (size_t)TJ * DIM_HEAD))[tid];
    vreg = *(const uint4*)(vg + (size_t)vrow * NTOK + TJ + vseg * 8);
    __syncthreads();

    const int NT = jlen / TJ;     // 16
    for (int t = 0; t < NT; ++t) {
        const int cur = t & 1;
        if (t + 1 < NT) {
            ((uint4*)lk[cur ^ 1])[tid] = kreg;
            *(uint4*)&lvt[cur ^ 1][vrow * VPAD + vseg * 8] = vreg;
            if (t + 2 < NT) {
                kreg = ((const uint4*)(kg + (size_t)(t + 2) * TJ * DIM_HEAD))[tid];
                vreg = *(const uint4*)(vg + (size_t)vrow * NTOK + (t + 2) * TJ + vseg * 8);
            }
        }
        // ---- QK^T swapped: sc[sub][r] = S[key=sub*16+lg*4+r][q=la] (log2 dom.) ----
        f32x4 sc[4];
        #pragma unroll
        for (int sub = 0; sub < 4; ++sub) {
            const half8 ak = *(const half8*)&lk[cur][(sub * 16 + la) * DIM_HEAD + lg * 8];
            f32x4 z = {0.f, 0.f, 0.f, 0.f};
            sc[sub] = __builtin_amdgcn_mfma_f32_16x16x32_f16(ak, aq, z, 0, 0, 0);
        }
        // ---- per-lane max over 16 regs + 2-shfl cross-replica reduce ----
        float tm = fmaxf(fmaxf(sc[0][0], sc[0][1]), fmaxf(sc[0][2], sc[0][3]));
        #pragma unroll
        for (int sub = 1; sub < 4; ++sub) {
            tm = fmaxf(tm, fmaxf(fmaxf(sc[sub][0], sc[sub][1]),
                                 fmaxf(sc[sub][2], sc[sub][3])));
        }
        tm = fmaxf(tm, __shfl_xor(tm, 16));
        tm = fmaxf(tm, __shfl_xor(tm, 32));
        // ---- defer-rescale: only when max moved by > 8 (log2) ----
        if (!__all(tm <= m + 8.f)) {
            const float mn   = fmaxf(m, tm);
            const float corr = exp2f(m - mn);
            m = mn;
            l *= corr;
            #pragma unroll
            for (int r = 0; r < 4; ++r) {
                const float cq = __shfl(corr, lg * 4 + r);
                acc0[r] *= cq;
                acc1[r] *= cq;
            }
        }
        // ---- probabilities: 16 exp2, packed b64 stores, XOR-swizzled units ----
        float ps = 0.f;
        #pragma unroll
        for (int sub = 0; sub < 4; ++sub) {
            union { _Float16 hp[4]; uint2 u; } pk;
            #pragma unroll
            for (int r = 0; r < 4; ++r) {
                const float p = exp2f(sc[sub][r] - m);
                ps += p;
                pk.hp[r] = (_Float16)p;
            }
            const int unit = (sub * 2 + (lg >> 1)) ^ (la & 7);
            *(uint2*)(pw + la * 128 + unit * 16 + (lg & 1) * 8) = pk.u;
        }
        l += ps;
        // ---- PV ----
        #pragma unroll
        for (int kc = 0; kc < 2; ++kc) {
            const int runit = (kc * 4 + lg) ^ (la & 7);
            const half8 pa = *(const half8*)(pw + la * 128 + runit * 16);
            const half8 v0 = *(const half8*)&lvt[cur][(la     ) * VPAD + kc * 32 + lg * 8];
            const half8 v1 = *(const half8*)&lvt[cur][(la + 16) * VPAD + kc * 32 + lg * 8];
            acc0 = __builtin_amdgcn_mfma_f32_16x16x32_f16(pa, v0, acc0, 0, 0, 0);
            acc1 = __builtin_amdgcn_mfma_f32_16x16x32_f16(pa, v1, acc1, 0, 0, 0);
        }
        __syncthreads();
    }
    float lt = l;
    lt += __shfl_xor(lt, 16);
    lt += __shfl_xor(lt, 32);
    const size_t pbase = (size_t)(h * JS + s) * NTOK + qbase;
    if (lane < 16) {
        pm[pbase + la] = m;
        pl[pbase + la] = lt;
    }
    #pragma unroll
    for (int r = 0; r < 4; ++r) {
        const size_t pq = pbase + lg * 4 + r;
        pacc[pq * DIM_HEAD + la     ] = acc0[r];
        pacc[pq * DIM_HEAD + la + 16] = acc1[r];
    }
}

// -------------------- 5. Combine partials (JS=4, exp2 domain) -> attT fp16 -----
__global__ void attn_combine4(const float* __restrict__ pm, const float* __restrict__ pl,
                              const float* __restrict__ pacc, _Float16* __restrict__ attT) {
    const int i = blockIdx.x * blockDim.x + threadIdx.x;   // 0..4095
    const int h = blockIdx.y;
    float mv[JS], lv[JS];
    float mM = -1e30f;
    #pragma unroll
    for (int s = 0; s < JS; ++s) {
        const size_t pidx = ((size_t)(h * JS + s) * NTOK + i);
        mv[s] = pm[pidx];
        lv[s] = pl[pidx];
        mM = fmaxf(mM, mv[s]);
    }
    float wv[JS];
    float denom = 0.f;
    #pragma unroll
    for (int s = 0; s < JS; ++s) {
        wv[s] = exp2f(mv[s] - mM);
        denom += lv[s] * wv[s];
    }
    const float inv = 1.f / denom;
    __attribute__((aligned(16))) _Float16 hv[DIM_HEAD];
    #pragma unroll
    for (int d0 = 0; d0 < DIM_HEAD; d0 += 4) {
        float o0 = 0.f, o1 = 0.f, o2 = 0.f, o3 = 0.f;
        #pragma unroll
        for (int s = 0; s < JS; ++s) {
            const size_t pidx = ((size_t)(h * JS + s) * NTOK + i);
            float4 a = *(const float4*)(pacc + pidx * DIM_HEAD + d0);
            o0 = fmaf(a.x, wv[s], o0);
            o1 = fmaf(a.y, wv[s], o1);
            o2 = fmaf(a.z, wv[s], o2);
            o3 = fmaf(a.w, wv[s], o3);
        }
        hv[d0]     = (_Float16)(o0 * inv);
        hv[d0 + 1] = (_Float16)(o1 * inv);
        hv[d0 + 2] = (_Float16)(o2 * inv);
        hv[d0 + 3] = (_Float16)(o3 * inv);
    }
    _Float16* dst = attT + (size_t)i * CCH + h * DIM_HEAD;   // 64 B contiguous
    #pragma unroll
    for (int q = 0; q < 4; ++q) ((uint4*)dst)[q] = ((const uint4*)hv)[q];
}

// -------------------- 6. Output projection via MFMA + bias + residual ----------
__global__ __launch_bounds__(256)
void out_mfma(const _Float16* __restrict__ wouth, const float* __restrict__ bo,
              const _Float16* __restrict__ attT, const float* __restrict__ x,
              float* __restrict__ out) {
    const int tid = threadIdx.x, w = tid >> 6, lane = tid & 63;
    const int la = lane & 15, lg = lane >> 4;
    const int jb = blockIdx.x * 64 + w * 16;
    const int ob = blockIdx.y * 16;
    const _Float16* arow = wouth + (size_t)(ob + la) * CCH;   // D row = o
    const _Float16* brow = attT  + (size_t)(jb + la) * CCH;   // D col = j
    f32x4 acc = {0.f, 0.f, 0.f, 0.f};
    #pragma unroll
    for (int kk = 0; kk < CCH; kk += 32) {
        const half8 a = *(const half8*)(arow + kk + lg * 8);
        const half8 b = *(const half8*)(brow + kk + lg * 8);
        acc = __builtin_amdgcn_mfma_f32_16x16x32_f16(a, b, acc, 0, 0, 0);
    }
    const float4 b4 = *(const float4*)(bo + ob + lg * 4);
    const float bb[4] = {b4.x, b4.y, b4.z, b4.w};
    #pragma unroll
    for (int r = 0; r < 4; ++r) {
        const int o = ob + lg * 4 + r;
        const size_t idx = (size_t)o * NTOK + jb + la;
        out[idx] = acc[r] + bb[r] + x[idx];
    }
}

extern "C" void kernel_launch(void* const* d_in, const int* in_sizes, int n_in,
                              void* d_out, int out_size, void* d_ws, size_t ws_size,
                              hipStream_t stream) {
    const float* x     = (const float*)d_in[0];
    const float* gamma = (const float*)d_in[1];
    const float* beta  = (const float*)d_in[2];
    const float* w_qkv = (const float*)d_in[3];
    const float* b_qkv = (const float*)d_in[4];
    const float* w_out = (const float*)d_in[5];
    const float* b_out = (const float*)d_in[6];
    float* out = (float*)d_out;

    float* ws   = (float*)d_ws;
    float* part = ws;                           // 512
    float* b2   = part + 512;                   // 768
    float* pm   = b2 + 768;                     // 8*4*4096 = 131072
    float* pl   = pm + 131072;                  // 131072
    float* pacc = pl + 131072;                  // 8*4*4096*32 = 4194304 (16 MB)
    float* fend = pacc + 4194304;
    _Float16* q_h   = (_Float16*)fend;          // 1048576 halves each
    _Float16* k_h   = q_h  + 1048576;
    _Float16* vT_h  = k_h  + 1048576;
    _Float16* xT    = vT_h + 1048576;           // 1048576
    _Float16* w2h   = xT   + 1048576;           // 196608
    _Float16* wouth = w2h  + 196608;            // 65536
    _Float16* attT  = wouth + 65536;            // 1048576
    // total ~29 MB (ws proven >= 92 MB in round 2)

    {
        dim3 g(GN_SPLIT, GROUPS);
        gn_stats_partial<<<g, 256, 0, stream>>>(x, part);
    }
    // fold + w_out convert + x transpose in one launch (blocks: 768 + 256 + 256)
    fold_qkv<<<5 * CCH, 256, 0, stream>>>(w_qkv, b_qkv, gamma, beta, part, w_out, x,
                                          w2h, b2, wouth, xT);
    {
        dim3 g(NTOK / 64, 3 * CCH / 16);
        qkv_mfma<<<g, 256, 0, stream>>>(w2h, b2, xT, q_h, k_h, vT_h);
    }
    {
        dim3 g(NTOK / 64, HEADS, JS);
        attn_mfma<<<g, 256, 0, stream>>>(q_h, k_h, vT_h, pm, pl, pacc);
    }
    {
        dim3 g(NTOK / 256, HEADS);
        attn_combine4<<<g, 256, 0, stream>>>(pm, pl, pacc, attT);
    }
    {
        dim3 g(NTOK / 64, CCH / 16);
        out_mfma<<<g, 256, 0, stream>>>(wouth, b_out, attT, x, out);
    }
}

// Round 16
// 99.800 us; speedup vs baseline: 1.0825x; 1.0825x over previous
//
#include <hip/hip_runtime.h>
#include <hip/hip_bf16.h>

#define HEADS 8
#define DIM_HEAD 32
#define GROUPS 8
#define CCH 256            // channels
#define NTOK 4096          // d*h*w = 16^3
#define EPS 1e-5f
#define GN_SPLIT 32
#define JS 4               // attention j-split

typedef _Float16 half8 __attribute__((ext_vector_type(8)));
typedef float f32x4 __attribute__((ext_vector_type(4)));

// -------------------- 1. GroupNorm partial stats --------------------
__global__ void gn_stats_partial(const float* __restrict__ x, float* __restrict__ part) {
    const int g  = blockIdx.y;
    const int sp = blockIdx.x;
    const int M = (CCH / GROUPS) * NTOK;        // 131072 contiguous floats per group
    const int chunk = M / GN_SPLIT;             // 4096
    const float4* p = (const float4*)(x + (size_t)g * M + (size_t)sp * chunk);
    float s = 0.f, ss = 0.f;
    for (int i = threadIdx.x; i < chunk / 4; i += blockDim.x) {
        float4 v = p[i];
        s  += v.x + v.y + v.z + v.w;
        ss += v.x*v.x + v.y*v.y + v.z*v.z + v.w*v.w;
    }
    #pragma unroll
    for (int off = 32; off; off >>= 1) {
        s  += __shfl_down(s,  off);
        ss += __shfl_down(ss, off);
    }
    __shared__ float sh0[8], sh1[8];
    const int wave = threadIdx.x >> 6, lane = threadIdx.x & 63;
    if (lane == 0) { sh0[wave] = s; sh1[wave] = ss; }
    __syncthreads();
    if (threadIdx.x == 0) {
        float S = 0.f, SS = 0.f;
        const int nw = blockDim.x >> 6;
        for (int w = 0; w < nw; ++w) { S += sh0[w]; SS += sh1[w]; }
        part[(g * GN_SPLIT + sp) * 2]     = S;
        part[(g * GN_SPLIT + sp) * 2 + 1] = SS;
    }
}

// -------------------- 2. Fold GN into QKV weights + w_out fp16 + x transpose ----
__global__ __launch_bounds__(256)
void fold_qkv(const float* __restrict__ w, const float* __restrict__ b,
              const float* __restrict__ gamma, const float* __restrict__ beta,
              const float* __restrict__ part, const float* __restrict__ w_out,
              const float* __restrict__ x,
              _Float16* __restrict__ w2h, float* __restrict__ b2,
              _Float16* __restrict__ wouth, _Float16* __restrict__ xT) {
    const int o = blockIdx.x;
    const int c = threadIdx.x;          // 0..255
    if (o >= 4 * CCH) {                 // ---- transpose tile ----
        const int t  = o - 4 * CCH;     // 0..255
        const int jb = (t & 63) * 64;
        const int cb = (t >> 6) * 64;
        __shared__ float tile[64][65];
        const int tj = threadIdx.x & 63, tc = threadIdx.x >> 6;
        #pragma unroll
        for (int cc = 0; cc < 64; cc += 4)
            tile[cc + tc][tj] = x[(size_t)(cb + cc + tc) * NTOK + jb + tj];
        __syncthreads();
        const int wc = threadIdx.x & 63, wj = threadIdx.x >> 6;
        #pragma unroll
        for (int jj = 0; jj < 64; jj += 4)
            xT[(size_t)(jb + jj + wj) * CCH + cb + wc] = (_Float16)tile[wc][jj + wj];
        return;
    }
    if (o >= 3 * CCH) {                 // ---- w_out convert ----
        const int oo = o - 3 * CCH;
        wouth[(size_t)oo * CCH + c] = (_Float16)w_out[(size_t)oo * CCH + c];
        return;
    }
    __shared__ float smean[GROUPS], srstd[GROUPS];
    if (c < GROUPS) {
        float s = 0.f, ss = 0.f;
        #pragma unroll
        for (int i = 0; i < GN_SPLIT; ++i) {
            s  += part[(c * GN_SPLIT + i) * 2];
            ss += part[(c * GN_SPLIT + i) * 2 + 1];
        }
        const float M = (float)((CCH / GROUPS) * NTOK);
        const float mean = s / M;
        const float var  = ss / M - mean * mean;
        smean[c] = mean;
        srstd[c] = rsqrtf(var + EPS);
    }
    __syncthreads();
    const int g = c >> 5;
    const float sc = gamma[c] * srstd[g];
    const float sh = beta[c] - smean[g] * sc;
    const float wv = w[(size_t)o * CCH + c];
    w2h[(size_t)o * CCH + c] = (_Float16)(wv * sc);
    float t = wv * sh;
    #pragma unroll
    for (int off = 32; off; off >>= 1) t += __shfl_down(t, off);
    __shared__ float shred[4];
    const int wave = threadIdx.x >> 6, lane = threadIdx.x & 63;
    if (lane == 0) shred[wave] = t;
    __syncthreads();
    if (threadIdx.x == 0)
        b2[o] = b[o] + shred[0] + shred[1] + shred[2] + shred[3];
}

// -------------------- 3. QKV GEMM via MFMA (R13-proven form) -------------------
__global__ __launch_bounds__(256)
void qkv_mfma(const _Float16* __restrict__ w2h, const float* __restrict__ b2,
              const _Float16* __restrict__ xT,
              _Float16* __restrict__ q_h, _Float16* __restrict__ k_h,
              _Float16* __restrict__ vT_h) {
    const int tid = threadIdx.x, w = tid >> 6, lane = tid & 63;
    const int la = lane & 15, lg = lane >> 4;
    const int jb = blockIdx.x * 64 + w * 16;   // wave's 16 tokens
    const int ob = blockIdx.y * 16;            // 16 output rows
    const int part = ob >> 8;
    f32x4 acc = {0.f, 0.f, 0.f, 0.f};
    if (part < 2) {
        // A = xT token rows (D row = j), B = w2h o-rows (D col = o)
        const _Float16* arow = xT  + (size_t)(jb + la) * CCH;
        const _Float16* brow = w2h + (size_t)(ob + la) * CCH;
        #pragma unroll
        for (int kk = 0; kk < CCH; kk += 32) {
            const half8 a = *(const half8*)(arow + kk + lg * 8);
            const half8 b = *(const half8*)(brow + kk + lg * 8);
            acc = __builtin_amdgcn_mfma_f32_16x16x32_f16(a, b, acc, 0, 0, 0);
        }
        const int h = (ob & 255) >> 5, dbase = ob & 31;
        const float bias = b2[ob + la];
        _Float16* dst = (part == 0) ? q_h : k_h;
        const float scl = (part == 0) ? 0.17677669529663687f : 1.0f;  // 32^-0.5
        #pragma unroll
        for (int r = 0; r < 4; ++r) {
            const int j = jb + lg * 4 + r;
            dst[((size_t)h * NTOK + j) * DIM_HEAD + dbase + la] =
                (_Float16)((acc[r] + bias) * scl);
        }
    } else {
        // A = w2h o-rows (D row = o=d), B = xT token rows (D col = j)
        const _Float16* arow = w2h + (size_t)(ob + la) * CCH;
        const _Float16* brow = xT  + (size_t)(jb + la) * CCH;
        #pragma unroll
        for (int kk = 0; kk < CCH; kk += 32) {
            const half8 a = *(const half8*)(arow + kk + lg * 8);
            const half8 b = *(const half8*)(brow + kk + lg * 8);
            acc = __builtin_amdgcn_mfma_f32_16x16x32_f16(a, b, acc, 0, 0, 0);
        }
        const int h = (ob & 255) >> 5, dbase = ob & 31;
        const float4 b4 = *(const float4*)(b2 + ob + lg * 4);
        const float bb[4] = {b4.x, b4.y, b4.z, b4.w};
        #pragma unroll
        for (int r = 0; r < 4; ++r) {
            const int d = dbase + lg * 4 + r;
            vT_h[((size_t)h * DIM_HEAD + d) * NTOK + jb + la] = (_Float16)(acc[r] + bb[r]);
        }
    }
}

// -------------------- 4. Flash attention partial: 8 waves/block ----------------
// R15 lesson: exp2+defer REGRESSED at matched occupancy (60.6 vs 54.8; the
// branch breaks cross-tile scheduling) — loop body reverted to R13-proven form.
// This round's single change: 512-thread blocks (8 waves). Same total waves and
// per-wave work, but LDS residency cap becomes 4 blocks x 8 = 32 waves/CU (100%
// vs 24), K/V staging serves 8 waves (block-level K/V fetch halves), and the
// dispatch has half the blocks.
#define TJ 64
#define VPAD 72
__global__ __launch_bounds__(512)
void attn_mfma(const _Float16* __restrict__ q_h, const _Float16* __restrict__ k_h,
               const _Float16* __restrict__ vT_h,
               float* __restrict__ pm, float* __restrict__ pl,
               float* __restrict__ pacc) {
    const int tid = threadIdx.x;                 // 0..511
    const int w = tid >> 6, lane = tid & 63;
    const int la = lane & 15, lg = lane >> 4;
    const int h = blockIdx.y;
    const int s = blockIdx.z;
    const int qbase = blockIdx.x * 128 + w * 16;
    const int jlen = NTOK / JS;          // 1024
    const int j0 = s * jlen;

    __shared__ _Float16 lk [2][TJ * DIM_HEAD];             // 2 x 4 KB
    __shared__ _Float16 lvt[2][DIM_HEAD * VPAD];           // 2 x 4.5 KB
    __shared__ __align__(16) _Float16 plds[8][16 * 64];    // 16 KB (per-wave P)

    const half8 aq = *(const half8*)(q_h + ((size_t)h * NTOK + qbase + la) * DIM_HEAD + lg * 8);

    f32x4 acc0 = {0.f, 0.f, 0.f, 0.f};
    f32x4 acc1 = {0.f, 0.f, 0.f, 0.f};
    float m = -1e30f, l = 0.f;           // per-lane: query la

    const _Float16* kg = k_h  + (size_t)h * NTOK * DIM_HEAD + (size_t)j0 * DIM_HEAD;
    const _Float16* vg = vT_h + (size_t)h * DIM_HEAD * NTOK + j0;
    // staging: K tile 4096B = 512 uint2 (1/thread); V region 32 rows x 64 halves,
    // vrow = tid>>4 (0..31), vseg = tid&15 (4-half units)
    const int vrow = tid >> 4, vseg = tid & 15;
    char* pw = (char*)&plds[w][0];

    uint2 kreg, vreg;
    kreg = ((const uint2*)kg)[tid];
    vreg = *(const uint2*)(vg + (size_t)vrow * NTOK + vseg * 4);
    ((uint2*)lk[0])[tid] = kreg;
    *(uint2*)&lvt[0][vrow * VPAD + vseg * 4] = vreg;
    kreg = ((const uint2*)(kg + (size_t)TJ * DIM_HEAD))[tid];
    vreg = *(const uint2*)(vg + (size_t)vrow * NTOK + TJ + vseg * 4);
    __syncthreads();

    const int NT = jlen / TJ;     // 16
    for (int t = 0; t < NT; ++t) {
        const int cur = t & 1;
        if (t + 1 < NT) {
            ((uint2*)lk[cur ^ 1])[tid] = kreg;
            *(uint2*)&lvt[cur ^ 1][vrow * VPAD + vseg * 4] = vreg;
            if (t + 2 < NT) {
                kreg = ((const uint2*)(kg + (size_t)(t + 2) * TJ * DIM_HEAD))[tid];
                vreg = *(const uint2*)(vg + (size_t)vrow * NTOK + (t + 2) * TJ + vseg * 4);
            }
        }
        // ---- QK^T swapped: sc[sub][r] = S[key=sub*16+lg*4+r][q=la] ----
        f32x4 sc[4];
        #pragma unroll
        for (int sub = 0; sub < 4; ++sub) {
            const half8 ak = *(const half8*)&lk[cur][(sub * 16 + la) * DIM_HEAD + lg * 8];
            f32x4 z = {0.f, 0.f, 0.f, 0.f};
            sc[sub] = __builtin_amdgcn_mfma_f32_16x16x32_f16(ak, aq, z, 0, 0, 0);
        }
        // ---- per-lane max over 16 regs + 2-shfl cross-replica reduce ----
        float tm = fmaxf(fmaxf(sc[0][0], sc[0][1]), fmaxf(sc[0][2], sc[0][3]));
        #pragma unroll
        for (int sub = 1; sub < 4; ++sub) {
            tm = fmaxf(tm, fmaxf(fmaxf(sc[sub][0], sc[sub][1]),
                                 fmaxf(sc[sub][2], sc[sub][3])));
        }
        tm = fmaxf(tm, __shfl_xor(tm, 16));
        tm = fmaxf(tm, __shfl_xor(tm, 32));
        const float mn   = fmaxf(m, tm);
        const float corr = __expf(m - mn);   // for query la
        m = mn;
        l *= corr;
        #pragma unroll
        for (int r = 0; r < 4; ++r) {
            const float cq = __shfl(corr, lg * 4 + r);
            acc0[r] *= cq;
            acc1[r] *= cq;
        }
        // ---- probabilities: 16 exps, packed b64 stores, XOR-swizzled units ----
        float ps = 0.f;
        #pragma unroll
        for (int sub = 0; sub < 4; ++sub) {
            union { _Float16 hp[4]; uint2 u; } pk;
            #pragma unroll
            for (int r = 0; r < 4; ++r) {
                const float p = __expf(sc[sub][r] - mn);
                ps += p;
                pk.hp[r] = (_Float16)p;
            }
            const int unit = (sub * 2 + (lg >> 1)) ^ (la & 7);
            *(uint2*)(pw + la * 128 + unit * 16 + (lg & 1) * 8) = pk.u;
        }
        l += ps;
        // ---- PV ----
        #pragma unroll
        for (int kc = 0; kc < 2; ++kc) {
            const int runit = (kc * 4 + lg) ^ (la & 7);
            const half8 pa = *(const half8*)(pw + la * 128 + runit * 16);
            const half8 v0 = *(const half8*)&lvt[cur][(la     ) * VPAD + kc * 32 + lg * 8];
            const half8 v1 = *(const half8*)&lvt[cur][(la + 16) * VPAD + kc * 32 + lg * 8];
            acc0 = __builtin_amdgcn_mfma_f32_16x16x32_f16(pa, v0, acc0, 0, 0, 0);
            acc1 = __builtin_amdgcn_mfma_f32_16x16x32_f16(pa, v1, acc1, 0, 0, 0);
        }
        __syncthreads();
    }
    // ---- epilogue: reduce l across the 4 replicas, store raw partial state ----
    float lt = l;
    lt += __shfl_xor(lt, 16);
    lt += __shfl_xor(lt, 32);
    const size_t pbase = (size_t)(h * JS + s) * NTOK + qbase;
    if (lane < 16) {
        pm[pbase + la] = m;
        pl[pbase + la] = lt;
    }
    #pragma unroll
    for (int r = 0; r < 4; ++r) {
        const size_t pq = pbase + lg * 4 + r;
        pacc[pq * DIM_HEAD + la     ] = acc0[r];
        pacc[pq * DIM_HEAD + la + 16] = acc1[r];
    }
}

// -------------------- 5. Combine partials (JS=4) -> attT fp16 ------------------
__global__ void attn_combine4(const float* __restrict__ pm, const float* __restrict__ pl,
                              const float* __restrict__ pacc, _Float16* __restrict__ attT) {
    const int i = blockIdx.x * blockDim.x + threadIdx.x;   // 0..4095
    const int h = blockIdx.y;
    float mv[JS], lv[JS];
    float mM = -1e30f;
    #pragma unroll
    for (int s = 0; s < JS; ++s) {
        const size_t pidx = ((size_t)(h * JS + s) * NTOK + i);
        mv[s] = pm[pidx];
        lv[s] = pl[pidx];
        mM = fmaxf(mM, mv[s]);
    }
    float wv[JS];
    float denom = 0.f;
    #pragma unroll
    for (int s = 0; s < JS; ++s) {
        wv[s] = __expf(mv[s] - mM);
        denom += lv[s] * wv[s];
    }
    const float inv = 1.f / denom;
    __attribute__((aligned(16))) _Float16 hv[DIM_HEAD];
    #pragma unroll
    for (int d0 = 0; d0 < DIM_HEAD; d0 += 4) {
        float o0 = 0.f, o1 = 0.f, o2 = 0.f, o3 = 0.f;
        #pragma unroll
        for (int s = 0; s < JS; ++s) {
            const size_t pidx = ((size_t)(h * JS + s) * NTOK + i);
            float4 a = *(const float4*)(pacc + pidx * DIM_HEAD + d0);
            o0 = fmaf(a.x, wv[s], o0);
            o1 = fmaf(a.y, wv[s], o1);
            o2 = fmaf(a.z, wv[s], o2);
            o3 = fmaf(a.w, wv[s], o3);
        }
        hv[d0]     = (_Float16)(o0 * inv);
        hv[d0 + 1] = (_Float16)(o1 * inv);
        hv[d0 + 2] = (_Float16)(o2 * inv);
        hv[d0 + 3] = (_Float16)(o3 * inv);
    }
    _Float16* dst = attT + (size_t)i * CCH + h * DIM_HEAD;   // 64 B contiguous
    #pragma unroll
    for (int q = 0; q < 4; ++q) ((uint4*)dst)[q] = ((const uint4*)hv)[q];
}

// -------------------- 6. Output projection via MFMA + bias + residual ----------
__global__ __launch_bounds__(256)
void out_mfma(const _Float16* __restrict__ wouth, const float* __restrict__ bo,
              const _Float16* __restrict__ attT, const float* __restrict__ x,
              float* __restrict__ out) {
    const int tid = threadIdx.x, w = tid >> 6, lane = tid & 63;
    const int la = lane & 15, lg = lane >> 4;
    const int jb = blockIdx.x * 64 + w * 16;
    const int ob = blockIdx.y * 16;
    const _Float16* arow = wouth + (size_t)(ob + la) * CCH;   // D row = o
    const _Float16* brow = attT  + (size_t)(jb + la) * CCH;   // D col = j
    f32x4 acc = {0.f, 0.f, 0.f, 0.f};
    #pragma unroll
    for (int kk = 0; kk < CCH; kk += 32) {
        const half8 a = *(const half8*)(arow + kk + lg * 8);
        const half8 b = *(const half8*)(brow + kk + lg * 8);
        acc = __builtin_amdgcn_mfma_f32_16x16x32_f16(a, b, acc, 0, 0, 0);
    }
    const float4 b4 = *(const float4*)(bo + ob + lg * 4);
    const float bb[4] = {b4.x, b4.y, b4.z, b4.w};
    #pragma unroll
    for (int r = 0; r < 4; ++r) {
        const int o = ob + lg * 4 + r;
        const size_t idx = (size_t)o * NTOK + jb + la;
        out[idx] = acc[r] + bb[r] + x[idx];
    }
}

extern "C" void kernel_launch(void* const* d_in, const int* in_sizes, int n_in,
                              void* d_out, int out_size, void* d_ws, size_t ws_size,
                              hipStream_t stream) {
    const float* x     = (const float*)d_in[0];
    const float* gamma = (const float*)d_in[1];
    const float* beta  = (const float*)d_in[2];
    const float* w_qkv = (const float*)d_in[3];
    const float* b_qkv = (const float*)d_in[4];
    const float* w_out = (const float*)d_in[5];
    const float* b_out = (const float*)d_in[6];
    float* out = (float*)d_out;

    float* ws   = (float*)d_ws;
    float* part = ws;                           // 512
    float* b2   = part + 512;                   // 768
    float* pm   = b2 + 768;                     // 8*4*4096 = 131072
    float* pl   = pm + 131072;                  // 131072
    float* pacc = pl + 131072;                  // 8*4*4096*32 = 4194304 (16 MB)
    float* fend = pacc + 4194304;
    _Float16* q_h   = (_Float16*)fend;          // 1048576 halves each
    _Float16* k_h   = q_h  + 1048576;
    _Float16* vT_h  = k_h  + 1048576;
    _Float16* xT    = vT_h + 1048576;           // 1048576
    _Float16* w2h   = xT   + 1048576;           // 196608
    _Float16* wouth = w2h  + 196608;            // 65536
    _Float16* attT  = wouth + 65536;            // 1048576
    // total ~29 MB (ws proven >= 92 MB in round 2)

    {
        dim3 g(GN_SPLIT, GROUPS);
        gn_stats_partial<<<g, 256, 0, stream>>>(x, part);
    }
    // fold + w_out convert + x transpose in one launch (blocks: 768 + 256 + 256)
    fold_qkv<<<5 * CCH, 256, 0, stream>>>(w_qkv, b_qkv, gamma, beta, part, w_out, x,
                                          w2h, b2, wouth, xT);
    {
        dim3 g(NTOK / 64, 3 * CCH / 16);
        qkv_mfma<<<g, 256, 0, stream>>>(w2h, b2, xT, q_h, k_h, vT_h);
    }
    {
        dim3 g(NTOK / 128, HEADS, JS);
        attn_mfma<<<g, 512, 0, stream>>>(q_h, k_h, vT_h, pm, pl, pacc);
    }
    {
        dim3 g(NTOK / 256, HEADS);
        attn_combine4<<<g, 256, 0, stream>>>(pm, pl, pacc, attT);
    }
    {
        dim3 g(NTOK / 64, CCH / 16);
        out_mfma<<<g, 256, 0, stream>>>(wouth, b_out, attT, x, out);
    }
}

// Round 17
// 95.487 us; speedup vs baseline: 1.1314x; 1.0452x over previous
//
#include <hip/hip_runtime.h>
#include <hip/hip_bf16.h>

#define HEADS 8
#define DIM_HEAD 32
#define GROUPS 8
#define CCH 256            // channels
#define NTOK 4096          // d*h*w = 16^3
#define EPS 1e-5f
#define GN_SPLIT 32
#define JS 4               // attention j-split

typedef _Float16 half8 __attribute__((ext_vector_type(8)));
typedef _Float16 half4 __attribute__((ext_vector_type(4)));
typedef float f32x4 __attribute__((ext_vector_type(4)));

// -------------------- 1. GroupNorm partial stats --------------------
__global__ void gn_stats_partial(const float* __restrict__ x, float* __restrict__ part) {
    const int g  = blockIdx.y;
    const int sp = blockIdx.x;
    const int M = (CCH / GROUPS) * NTOK;        // 131072 contiguous floats per group
    const int chunk = M / GN_SPLIT;             // 4096
    const float4* p = (const float4*)(x + (size_t)g * M + (size_t)sp * chunk);
    float s = 0.f, ss = 0.f;
    for (int i = threadIdx.x; i < chunk / 4; i += blockDim.x) {
        float4 v = p[i];
        s  += v.x + v.y + v.z + v.w;
        ss += v.x*v.x + v.y*v.y + v.z*v.z + v.w*v.w;
    }
    #pragma unroll
    for (int off = 32; off; off >>= 1) {
        s  += __shfl_down(s,  off);
        ss += __shfl_down(ss, off);
    }
    __shared__ float sh0[8], sh1[8];
    const int wave = threadIdx.x >> 6, lane = threadIdx.x & 63;
    if (lane == 0) { sh0[wave] = s; sh1[wave] = ss; }
    __syncthreads();
    if (threadIdx.x == 0) {
        float S = 0.f, SS = 0.f;
        const int nw = blockDim.x >> 6;
        for (int w = 0; w < nw; ++w) { S += sh0[w]; SS += sh1[w]; }
        part[(g * GN_SPLIT + sp) * 2]     = S;
        part[(g * GN_SPLIT + sp) * 2 + 1] = SS;
    }
}

// -------------------- 2. Fold GN into QKV weights + w_out fp16 + x transpose ----
__global__ __launch_bounds__(256)
void fold_qkv(const float* __restrict__ w, const float* __restrict__ b,
              const float* __restrict__ gamma, const float* __restrict__ beta,
              const float* __restrict__ part, const float* __restrict__ w_out,
              const float* __restrict__ x,
              _Float16* __restrict__ w2h, float* __restrict__ b2,
              _Float16* __restrict__ wouth, _Float16* __restrict__ xT) {
    const int o = blockIdx.x;
    const int c = threadIdx.x;          // 0..255
    if (o >= 4 * CCH) {                 // ---- transpose tile ----
        const int t  = o - 4 * CCH;     // 0..255
        const int jb = (t & 63) * 64;
        const int cb = (t >> 6) * 64;
        __shared__ float tile[64][65];
        const int tj = threadIdx.x & 63, tc = threadIdx.x >> 6;
        #pragma unroll
        for (int cc = 0; cc < 64; cc += 4)
            tile[cc + tc][tj] = x[(size_t)(cb + cc + tc) * NTOK + jb + tj];
        __syncthreads();
        const int wc = threadIdx.x & 63, wj = threadIdx.x >> 6;
        #pragma unroll
        for (int jj = 0; jj < 64; jj += 4)
            xT[(size_t)(jb + jj + wj) * CCH + cb + wc] = (_Float16)tile[wc][jj + wj];
        return;
    }
    if (o >= 3 * CCH) {                 // ---- w_out convert ----
        const int oo = o - 3 * CCH;
        wouth[(size_t)oo * CCH + c] = (_Float16)w_out[(size_t)oo * CCH + c];
        return;
    }
    __shared__ float smean[GROUPS], srstd[GROUPS];
    if (c < GROUPS) {
        float s = 0.f, ss = 0.f;
        #pragma unroll
        for (int i = 0; i < GN_SPLIT; ++i) {
            s  += part[(c * GN_SPLIT + i) * 2];
            ss += part[(c * GN_SPLIT + i) * 2 + 1];
        }
        const float M = (float)((CCH / GROUPS) * NTOK);
        const float mean = s / M;
        const float var  = ss / M - mean * mean;
        smean[c] = mean;
        srstd[c] = rsqrtf(var + EPS);
    }
    __syncthreads();
    const int g = c >> 5;
    const float sc = gamma[c] * srstd[g];
    const float sh = beta[c] - smean[g] * sc;
    const float wv = w[(size_t)o * CCH + c];
    w2h[(size_t)o * CCH + c] = (_Float16)(wv * sc);
    float t = wv * sh;
    #pragma unroll
    for (int off = 32; off; off >>= 1) t += __shfl_down(t, off);
    __shared__ float shred[4];
    const int wave = threadIdx.x >> 6, lane = threadIdx.x & 63;
    if (lane == 0) shred[wave] = t;
    __syncthreads();
    if (threadIdx.x == 0)
        b2[o] = b[o] + shred[0] + shred[1] + shred[2] + shred[3];
}

// -------------------- 3. QKV GEMM via MFMA (R13-proven form) -------------------
__global__ __launch_bounds__(256)
void qkv_mfma(const _Float16* __restrict__ w2h, const float* __restrict__ b2,
              const _Float16* __restrict__ xT,
              _Float16* __restrict__ q_h, _Float16* __restrict__ k_h,
              _Float16* __restrict__ vT_h) {
    const int tid = threadIdx.x, w = tid >> 6, lane = tid & 63;
    const int la = lane & 15, lg = lane >> 4;
    const int jb = blockIdx.x * 64 + w * 16;   // wave's 16 tokens
    const int ob = blockIdx.y * 16;            // 16 output rows
    const int part = ob >> 8;
    f32x4 acc = {0.f, 0.f, 0.f, 0.f};
    if (part < 2) {
        // A = xT token rows (D row = j), B = w2h o-rows (D col = o)
        const _Float16* arow = xT  + (size_t)(jb + la) * CCH;
        const _Float16* brow = w2h + (size_t)(ob + la) * CCH;
        #pragma unroll
        for (int kk = 0; kk < CCH; kk += 32) {
            const half8 a = *(const half8*)(arow + kk + lg * 8);
            const half8 b = *(const half8*)(brow + kk + lg * 8);
            acc = __builtin_amdgcn_mfma_f32_16x16x32_f16(a, b, acc, 0, 0, 0);
        }
        const int h = (ob & 255) >> 5, dbase = ob & 31;
        const float bias = b2[ob + la];
        _Float16* dst = (part == 0) ? q_h : k_h;
        const float scl = (part == 0) ? 0.17677669529663687f : 1.0f;  // 32^-0.5
        #pragma unroll
        for (int r = 0; r < 4; ++r) {
            const int j = jb + lg * 4 + r;
            dst[((size_t)h * NTOK + j) * DIM_HEAD + dbase + la] =
                (_Float16)((acc[r] + bias) * scl);
        }
    } else {
        // A = w2h o-rows (D row = o=d), B = xT token rows (D col = j)
        const _Float16* arow = w2h + (size_t)(ob + la) * CCH;
        const _Float16* brow = xT  + (size_t)(jb + la) * CCH;
        #pragma unroll
        for (int kk = 0; kk < CCH; kk += 32) {
            const half8 a = *(const half8*)(arow + kk + lg * 8);
            const half8 b = *(const half8*)(brow + kk + lg * 8);
            acc = __builtin_amdgcn_mfma_f32_16x16x32_f16(a, b, acc, 0, 0, 0);
        }
        const int h = (ob & 255) >> 5, dbase = ob & 31;
        const float4 b4 = *(const float4*)(b2 + ob + lg * 4);
        const float bb[4] = {b4.x, b4.y, b4.z, b4.w};
        #pragma unroll
        for (int r = 0; r < 4; ++r) {
            const int d = dbase + lg * 4 + r;
            vT_h[((size_t)h * DIM_HEAD + d) * NTOK + jb + la] = (_Float16)(acc[r] + bb[r]);
        }
    }
}

// -------------------- 4. Flash attention partial: 8 waves, K-pad 36 ------------
// R16 DS-model: kernel is LDS-pipe-bound; ak reads on 64B K rows hit ~8-way bank
// conflicts (bank = 16(la&1)+4lg, 8 distinct/64 lanes). Pad K row stride to 36
// halves (72B): bank = (18la+4lg) mod 32 -> 16 distinct, <=2-way (free, m136).
// Global staging reads stay fully coalesced (only LDS dest is strided).
// pacc demoted to fp16 (halves partial-state traffic; ~5e-4 rel).
#define TJ 64
#define KPAD 36
#define VPAD 72
__global__ __launch_bounds__(512)
void attn_mfma(const _Float16* __restrict__ q_h, const _Float16* __restrict__ k_h,
               const _Float16* __restrict__ vT_h,
               float* __restrict__ pm, float* __restrict__ pl,
               _Float16* __restrict__ pacc) {
    const int tid = threadIdx.x;                 // 0..511
    const int w = tid >> 6, lane = tid & 63;
    const int la = lane & 15, lg = lane >> 4;
    const int h = blockIdx.y;
    const int s = blockIdx.z;
    const int qbase = blockIdx.x * 128 + w * 16;
    const int jlen = NTOK / JS;          // 1024
    const int j0 = s * jlen;

    __shared__ _Float16 lk [2][TJ * KPAD];                 // 2 x 4.5 KB
    __shared__ _Float16 lvt[2][DIM_HEAD * VPAD];           // 2 x 4.5 KB
    __shared__ __align__(16) _Float16 plds[8][16 * 64];    // 16 KB (per-wave P)

    const half8 aq = *(const half8*)(q_h + ((size_t)h * NTOK + qbase + la) * DIM_HEAD + lg * 8);

    f32x4 acc0 = {0.f, 0.f, 0.f, 0.f};
    f32x4 acc1 = {0.f, 0.f, 0.f, 0.f};
    float m = -1e30f, l = 0.f;           // per-lane: query la

    const _Float16* kg = k_h  + (size_t)h * NTOK * DIM_HEAD + (size_t)j0 * DIM_HEAD;
    const _Float16* vg = vT_h + (size_t)h * DIM_HEAD * NTOK + j0;
    // K staging: thread tid stages row tid>>3 (global 64B rows), 8B chunk tid&7.
    const int krow = tid >> 3, kc8 = tid & 7;
    // V staging: vrow = tid>>4 (0..31), vseg = tid&15 (4-half units)
    const int vrow = tid >> 4, vseg = tid & 15;
    char* pw = (char*)&plds[w][0];

    uint2 kreg, vreg;
    kreg = ((const uint2*)kg)[tid];
    vreg = *(const uint2*)(vg + (size_t)vrow * NTOK + vseg * 4);
    *(uint2*)&lk[0][krow * KPAD + kc8 * 4] = kreg;
    *(uint2*)&lvt[0][vrow * VPAD + vseg * 4] = vreg;
    kreg = ((const uint2*)(kg + (size_t)TJ * DIM_HEAD))[tid];
    vreg = *(const uint2*)(vg + (size_t)vrow * NTOK + TJ + vseg * 4);
    __syncthreads();

    const int NT = jlen / TJ;     // 16
    for (int t = 0; t < NT; ++t) {
        const int cur = t & 1;
        if (t + 1 < NT) {
            *(uint2*)&lk[cur ^ 1][krow * KPAD + kc8 * 4] = kreg;
            *(uint2*)&lvt[cur ^ 1][vrow * VPAD + vseg * 4] = vreg;
            if (t + 2 < NT) {
                kreg = ((const uint2*)(kg + (size_t)(t + 2) * TJ * DIM_HEAD))[tid];
                vreg = *(const uint2*)(vg + (size_t)vrow * NTOK + (t + 2) * TJ + vseg * 4);
            }
        }
        // ---- QK^T swapped: sc[sub][r] = S[key=sub*16+lg*4+r][q=la] ----
        f32x4 sc[4];
        #pragma unroll
        for (int sub = 0; sub < 4; ++sub) {
            const half8 ak = *(const half8*)&lk[cur][(sub * 16 + la) * KPAD + lg * 8];
            f32x4 z = {0.f, 0.f, 0.f, 0.f};
            sc[sub] = __builtin_amdgcn_mfma_f32_16x16x32_f16(ak, aq, z, 0, 0, 0);
        }
        // ---- per-lane max over 16 regs + 2-shfl cross-replica reduce ----
        float tm = fmaxf(fmaxf(sc[0][0], sc[0][1]), fmaxf(sc[0][2], sc[0][3]));
        #pragma unroll
        for (int sub = 1; sub < 4; ++sub) {
            tm = fmaxf(tm, fmaxf(fmaxf(sc[sub][0], sc[sub][1]),
                                 fmaxf(sc[sub][2], sc[sub][3])));
        }
        tm = fmaxf(tm, __shfl_xor(tm, 16));
        tm = fmaxf(tm, __shfl_xor(tm, 32));
        const float mn   = fmaxf(m, tm);
        const float corr = __expf(m - mn);   // for query la
        m = mn;
        l *= corr;
        #pragma unroll
        for (int r = 0; r < 4; ++r) {
            const float cq = __shfl(corr, lg * 4 + r);
            acc0[r] *= cq;
            acc1[r] *= cq;
        }
        // ---- probabilities: 16 exps, packed b64 stores, XOR-swizzled units ----
        float ps = 0.f;
        #pragma unroll
        for (int sub = 0; sub < 4; ++sub) {
            union { _Float16 hp[4]; uint2 u; } pk;
            #pragma unroll
            for (int r = 0; r < 4; ++r) {
                const float p = __expf(sc[sub][r] - mn);
                ps += p;
                pk.hp[r] = (_Float16)p;
            }
            const int unit = (sub * 2 + (lg >> 1)) ^ (la & 7);
            *(uint2*)(pw + la * 128 + unit * 16 + (lg & 1) * 8) = pk.u;
        }
        l += ps;
        // ---- PV ----
        #pragma unroll
        for (int kc = 0; kc < 2; ++kc) {
            const int runit = (kc * 4 + lg) ^ (la & 7);
            const half8 pa = *(const half8*)(pw + la * 128 + runit * 16);
            const half8 v0 = *(const half8*)&lvt[cur][(la     ) * VPAD + kc * 32 + lg * 8];
            const half8 v1 = *(const half8*)&lvt[cur][(la + 16) * VPAD + kc * 32 + lg * 8];
            acc0 = __builtin_amdgcn_mfma_f32_16x16x32_f16(pa, v0, acc0, 0, 0, 0);
            acc1 = __builtin_amdgcn_mfma_f32_16x16x32_f16(pa, v1, acc1, 0, 0, 0);
        }
        __syncthreads();
    }
    // ---- epilogue: reduce l across the 4 replicas, store partial state --------
    float lt = l;
    lt += __shfl_xor(lt, 16);
    lt += __shfl_xor(lt, 32);
    const size_t pbase = (size_t)(h * JS + s) * NTOK + qbase;
    if (lane < 16) {
        pm[pbase + la] = m;
        pl[pbase + la] = lt;
    }
    #pragma unroll
    for (int r = 0; r < 4; ++r) {
        const size_t pq = pbase + lg * 4 + r;
        pacc[pq * DIM_HEAD + la     ] = (_Float16)acc0[r];
        pacc[pq * DIM_HEAD + la + 16] = (_Float16)acc1[r];
    }
}

// -------------------- 5. Combine partials (JS=4, fp16 pacc) -> attT fp16 -------
__global__ void attn_combine4(const float* __restrict__ pm, const float* __restrict__ pl,
                              const _Float16* __restrict__ pacc, _Float16* __restrict__ attT) {
    const int i = blockIdx.x * blockDim.x + threadIdx.x;   // 0..4095
    const int h = blockIdx.y;
    float mv[JS], lv[JS];
    float mM = -1e30f;
    #pragma unroll
    for (int s = 0; s < JS; ++s) {
        const size_t pidx = ((size_t)(h * JS + s) * NTOK + i);
        mv[s] = pm[pidx];
        lv[s] = pl[pidx];
        mM = fmaxf(mM, mv[s]);
    }
    float wv[JS];
    float denom = 0.f;
    #pragma unroll
    for (int s = 0; s < JS; ++s) {
        wv[s] = __expf(mv[s] - mM);
        denom += lv[s] * wv[s];
    }
    const float inv = 1.f / denom;
    __attribute__((aligned(16))) _Float16 hv[DIM_HEAD];
    #pragma unroll
    for (int d0 = 0; d0 < DIM_HEAD; d0 += 4) {
        float o0 = 0.f, o1 = 0.f, o2 = 0.f, o3 = 0.f;
        #pragma unroll
        for (int s = 0; s < JS; ++s) {
            const size_t pidx = ((size_t)(h * JS + s) * NTOK + i);
            const half4 a = *(const half4*)(pacc + pidx * DIM_HEAD + d0);
            o0 = fmaf((float)a.x, wv[s], o0);
            o1 = fmaf((float)a.y, wv[s], o1);
            o2 = fmaf((float)a.z, wv[s], o2);
            o3 = fmaf((float)a.w, wv[s], o3);
        }
        hv[d0]     = (_Float16)(o0 * inv);
        hv[d0 + 1] = (_Float16)(o1 * inv);
        hv[d0 + 2] = (_Float16)(o2 * inv);
        hv[d0 + 3] = (_Float16)(o3 * inv);
    }
    _Float16* dst = attT + (size_t)i * CCH + h * DIM_HEAD;   // 64 B contiguous
    #pragma unroll
    for (int q = 0; q < 4; ++q) ((uint4*)dst)[q] = ((const uint4*)hv)[q];
}

// -------------------- 6. Output projection via MFMA + bias + residual ----------
__global__ __launch_bounds__(256)
void out_mfma(const _Float16* __restrict__ wouth, const float* __restrict__ bo,
              const _Float16* __restrict__ attT, const float* __restrict__ x,
              float* __restrict__ out) {
    const int tid = threadIdx.x, w = tid >> 6, lane = tid & 63;
    const int la = lane & 15, lg = lane >> 4;
    const int jb = blockIdx.x * 64 + w * 16;
    const int ob = blockIdx.y * 16;
    const _Float16* arow = wouth + (size_t)(ob + la) * CCH;   // D row = o
    const _Float16* brow = attT  + (size_t)(jb + la) * CCH;   // D col = j
    f32x4 acc = {0.f, 0.f, 0.f, 0.f};
    #pragma unroll
    for (int kk = 0; kk < CCH; kk += 32) {
        const half8 a = *(const half8*)(arow + kk + lg * 8);
        const half8 b = *(const half8*)(brow + kk + lg * 8);
        acc = __builtin_amdgcn_mfma_f32_16x16x32_f16(a, b, acc, 0, 0, 0);
    }
    const float4 b4 = *(const float4*)(bo + ob + lg * 4);
    const float bb[4] = {b4.x, b4.y, b4.z, b4.w};
    #pragma unroll
    for (int r = 0; r < 4; ++r) {
        const int o = ob + lg * 4 + r;
        const size_t idx = (size_t)o * NTOK + jb + la;
        out[idx] = acc[r] + bb[r] + x[idx];
    }
}

extern "C" void kernel_launch(void* const* d_in, const int* in_sizes, int n_in,
                              void* d_out, int out_size, void* d_ws, size_t ws_size,
                              hipStream_t stream) {
    const float* x     = (const float*)d_in[0];
    const float* gamma = (const float*)d_in[1];
    const float* beta  = (const float*)d_in[2];
    const float* w_qkv = (const float*)d_in[3];
    const float* b_qkv = (const float*)d_in[4];
    const float* w_out = (const float*)d_in[5];
    const float* b_out = (const float*)d_in[6];
    float* out = (float*)d_out;

    float* ws   = (float*)d_ws;
    float* part = ws;                           // 512
    float* b2   = part + 512;                   // 768
    float* pm   = b2 + 768;                     // 8*4*4096 = 131072
    float* pl   = pm + 131072;                  // 131072
    _Float16* pacc = (_Float16*)(pl + 131072);  // 8*4*4096*32 halves (8.4 MB)
    float* fend = pl + 131072 + 2097152;        // pacc = 2097152 floats worth
    _Float16* q_h   = (_Float16*)fend;          // 1048576 halves each
    _Float16* k_h   = q_h  + 1048576;
    _Float16* vT_h  = k_h  + 1048576;
    _Float16* xT    = vT_h + 1048576;           // 1048576
    _Float16* w2h   = xT   + 1048576;           // 196608
    _Float16* wouth = w2h  + 196608;            // 65536
    _Float16* attT  = wouth + 65536;            // 1048576
    // total ~21 MB (ws proven >= 92 MB in round 2)

    {
        dim3 g(GN_SPLIT, GROUPS);
        gn_stats_partial<<<g, 256, 0, stream>>>(x, part);
    }
    // fold + w_out convert + x transpose in one launch (blocks: 768 + 256 + 256)
    fold_qkv<<<5 * CCH, 256, 0, stream>>>(w_qkv, b_qkv, gamma, beta, part, w_out, x,
                                          w2h, b2, wouth, xT);
    {
        dim3 g(NTOK / 64, 3 * CCH / 16);
        qkv_mfma<<<g, 256, 0, stream>>>(w2h, b2, xT, q_h, k_h, vT_h);
    }
    {
        dim3 g(NTOK / 128, HEADS, JS);
        attn_mfma<<<g, 512, 0, stream>>>(q_h, k_h, vT_h, pm, pl, pacc);
    }
    {
        dim3 g(NTOK / 256, HEADS);
        attn_combine4<<<g, 256, 0, stream>>>(pm, pl, pacc, attT);
    }
    {
        dim3 g(NTOK / 64, CCH / 16);
        out_mfma<<<g, 256, 0, stream>>>(wouth, b_out, attT, x, out);
    }
}

// Round 19
// 88.945 us; speedup vs baseline: 1.2146x; 1.0736x over previous
//
#include <hip/hip_runtime.h>
#include <hip/hip_bf16.h>

#define HEADS 8
#define DIM_HEAD 32
#define GROUPS 8
#define CCH 256            // channels
#define NTOK 4096          // d*h*w = 16^3
#define EPS 1e-5f
#define GN_SPLIT 32
#define JS 8               // attention j-split

typedef _Float16 half8 __attribute__((ext_vector_type(8)));
typedef _Float16 half4 __attribute__((ext_vector_type(4)));
typedef __fp16   fp16x2 __attribute__((ext_vector_type(2)));   // cvt_pkrtz return type
typedef float f32x4 __attribute__((ext_vector_type(4)));
typedef float f32x16 __attribute__((ext_vector_type(16)));

// -------------------- 1. GroupNorm partial stats --------------------
__global__ void gn_stats_partial(const float* __restrict__ x, float* __restrict__ part) {
    const int g  = blockIdx.y;
    const int sp = blockIdx.x;
    const int M = (CCH / GROUPS) * NTOK;        // 131072 contiguous floats per group
    const int chunk = M / GN_SPLIT;             // 4096
    const float4* p = (const float4*)(x + (size_t)g * M + (size_t)sp * chunk);
    float s = 0.f, ss = 0.f;
    for (int i = threadIdx.x; i < chunk / 4; i += blockDim.x) {
        float4 v = p[i];
        s  += v.x + v.y + v.z + v.w;
        ss += v.x*v.x + v.y*v.y + v.z*v.z + v.w*v.w;
    }
    #pragma unroll
    for (int off = 32; off; off >>= 1) {
        s  += __shfl_down(s,  off);
        ss += __shfl_down(ss, off);
    }
    __shared__ float sh0[8], sh1[8];
    const int wave = threadIdx.x >> 6, lane = threadIdx.x & 63;
    if (lane == 0) { sh0[wave] = s; sh1[wave] = ss; }
    __syncthreads();
    if (threadIdx.x == 0) {
        float S = 0.f, SS = 0.f;
        const int nw = blockDim.x >> 6;
        for (int w = 0; w < nw; ++w) { S += sh0[w]; SS += sh1[w]; }
        part[(g * GN_SPLIT + sp) * 2]     = S;
        part[(g * GN_SPLIT + sp) * 2 + 1] = SS;
    }
}

// -------------------- 2. Fold GN into QKV weights + w_out fp16 + x transpose ----
__global__ __launch_bounds__(256)
void fold_qkv(const float* __restrict__ w, const float* __restrict__ b,
              const float* __restrict__ gamma, const float* __restrict__ beta,
              const float* __restrict__ part, const float* __restrict__ w_out,
              const float* __restrict__ x,
              _Float16* __restrict__ w2h, float* __restrict__ b2,
              _Float16* __restrict__ wouth, _Float16* __restrict__ xT) {
    const int o = blockIdx.x;
    const int c = threadIdx.x;          // 0..255
    if (o >= 4 * CCH) {                 // ---- transpose tile ----
        const int t  = o - 4 * CCH;     // 0..255
        const int jb = (t & 63) * 64;
        const int cb = (t >> 6) * 64;
        __shared__ float tile[64][65];
        const int tj = threadIdx.x & 63, tc = threadIdx.x >> 6;
        #pragma unroll
        for (int cc = 0; cc < 64; cc += 4)
            tile[cc + tc][tj] = x[(size_t)(cb + cc + tc) * NTOK + jb + tj];
        __syncthreads();
        const int wc = threadIdx.x & 63, wj = threadIdx.x >> 6;
        #pragma unroll
        for (int jj = 0; jj < 64; jj += 4)
            xT[(size_t)(jb + jj + wj) * CCH + cb + wc] = (_Float16)tile[wc][jj + wj];
        return;
    }
    if (o >= 3 * CCH) {                 // ---- w_out convert ----
        const int oo = o - 3 * CCH;
        wouth[(size_t)oo * CCH + c] = (_Float16)w_out[(size_t)oo * CCH + c];
        return;
    }
    __shared__ float smean[GROUPS], srstd[GROUPS];
    if (c < GROUPS) {
        float s = 0.f, ss = 0.f;
        #pragma unroll
        for (int i = 0; i < GN_SPLIT; ++i) {
            s  += part[(c * GN_SPLIT + i) * 2];
            ss += part[(c * GN_SPLIT + i) * 2 + 1];
        }
        const float M = (float)((CCH / GROUPS) * NTOK);
        const float mean = s / M;
        const float var  = ss / M - mean * mean;
        smean[c] = mean;
        srstd[c] = rsqrtf(var + EPS);
    }
    __syncthreads();
    const int g = c >> 5;
    const float sc = gamma[c] * srstd[g];
    const float sh = beta[c] - smean[g] * sc;
    const float wv = w[(size_t)o * CCH + c];
    w2h[(size_t)o * CCH + c] = (_Float16)(wv * sc);
    float t = wv * sh;
    #pragma unroll
    for (int off = 32; off; off >>= 1) t += __shfl_down(t, off);
    __shared__ float shred[4];
    const int wave = threadIdx.x >> 6, lane = threadIdx.x & 63;
    if (lane == 0) shred[wave] = t;
    __syncthreads();
    if (threadIdx.x == 0)
        b2[o] = b[o] + shred[0] + shred[1] + shred[2] + shred[3];
}

// -------------------- 3. QKV GEMM via MFMA (R13-proven form) -------------------
__global__ __launch_bounds__(256)
void qkv_mfma(const _Float16* __restrict__ w2h, const float* __restrict__ b2,
              const _Float16* __restrict__ xT,
              _Float16* __restrict__ q_h, _Float16* __restrict__ k_h,
              _Float16* __restrict__ vT_h) {
    const int tid = threadIdx.x, w = tid >> 6, lane = tid & 63;
    const int la = lane & 15, lg = lane >> 4;
    const int jb = blockIdx.x * 64 + w * 16;   // wave's 16 tokens
    const int ob = blockIdx.y * 16;            // 16 output rows
    const int part = ob >> 8;
    f32x4 acc = {0.f, 0.f, 0.f, 0.f};
    if (part < 2) {
        const _Float16* arow = xT  + (size_t)(jb + la) * CCH;
        const _Float16* brow = w2h + (size_t)(ob + la) * CCH;
        #pragma unroll
        for (int kk = 0; kk < CCH; kk += 32) {
            const half8 a = *(const half8*)(arow + kk + lg * 8);
            const half8 b = *(const half8*)(brow + kk + lg * 8);
            acc = __builtin_amdgcn_mfma_f32_16x16x32_f16(a, b, acc, 0, 0, 0);
        }
        const int h = (ob & 255) >> 5, dbase = ob & 31;
        const float bias = b2[ob + la];
        _Float16* dst = (part == 0) ? q_h : k_h;
        const float scl = (part == 0) ? 0.17677669529663687f : 1.0f;  // 32^-0.5
        #pragma unroll
        for (int r = 0; r < 4; ++r) {
            const int j = jb + lg * 4 + r;
            dst[((size_t)h * NTOK + j) * DIM_HEAD + dbase + la] =
                (_Float16)((acc[r] + bias) * scl);
        }
    } else {
        const _Float16* arow = w2h + (size_t)(ob + la) * CCH;
        const _Float16* brow = xT  + (size_t)(jb + la) * CCH;
        #pragma unroll
        for (int kk = 0; kk < CCH; kk += 32) {
            const half8 a = *(const half8*)(arow + kk + lg * 8);
            const half8 b = *(const half8*)(brow + kk + lg * 8);
            acc = __builtin_amdgcn_mfma_f32_16x16x32_f16(a, b, acc, 0, 0, 0);
        }
        const int h = (ob & 255) >> 5, dbase = ob & 31;
        const float4 b4 = *(const float4*)(b2 + ob + lg * 4);
        const float bb[4] = {b4.x, b4.y, b4.z, b4.w};
        #pragma unroll
        for (int r = 0; r < 4; ++r) {
            const int d = dbase + lg * 4 + r;
            vT_h[((size_t)h * DIM_HEAD + d) * NTOK + jb + la] = (_Float16)(acc[r] + bb[r]);
        }
    }
}

// -------------------- 4. Flash attention: 32x32 MFMA, P in registers (T12) -----
// R17 verdict: DS-pipe-bound; 6 of 16 DS ops/wave-tile were the P LDS round-trip.
// Restructure: 32 queries/wave via mfma_f32_32x32x16_f16. Swapped QK^T -> lane
// q=lane&31 owns 32 scores (2 groups x 16 regs; key = 32kg+(reg&3)+8(reg>>2)+4hi).
// P redistributed IN-REGISTER: cvt_pkrtz pairs + 2x v_permlane32_swap per chunk
// gives both hi/lo lanes the exact PV B-fragment {A,B,C,D}. PV computed output-
// transposed (A=V^T d-rows, B=P q-rows -> D[d][q]) so m/l/corr stay lane-local.
// DS/wave-tile: 10 (was 16) for 2x queries; plds deleted (LDS 34.8->18.4 KB).
#define TJ 64
#define KPAD 36
#define VPAD 72
__global__ __launch_bounds__(512)
void attn_mfma(const _Float16* __restrict__ q_h, const _Float16* __restrict__ k_h,
               const _Float16* __restrict__ vT_h,
               float* __restrict__ pm, float* __restrict__ pl,
               _Float16* __restrict__ pacc) {
    const int tid = threadIdx.x;                 // 0..511
    const int w = tid >> 6, lane = tid & 63;
    const int la32 = lane & 31, hi = lane >> 5;
    const int h = blockIdx.y;
    const int s = blockIdx.z;
    const int qbase = blockIdx.x * 256 + w * 32;
    const int jlen = NTOK / JS;          // 512
    const int j0 = s * jlen;

    __shared__ _Float16 lk [2][TJ * KPAD];           // 2 x 4.5 KB (64 key rows)
    __shared__ _Float16 lvt[2][DIM_HEAD * VPAD];     // 2 x 4.5 KB (32 d rows)

    // Q B-fragments: lane holds Q row q=la32, d = c16*16 + hi*8 .. +7
    const _Float16* qrow = q_h + ((size_t)h * NTOK + qbase + la32) * DIM_HEAD;
    const half8 bq0 = *(const half8*)(qrow + hi * 8);
    const half8 bq1 = *(const half8*)(qrow + 16 + hi * 8);

    f32x16 acc;
    #pragma unroll
    for (int r = 0; r < 16; ++r) acc[r] = 0.f;
    float m = -1e30f, l = 0.f;           // per-lane: query la32 (replicated in hi)

    const _Float16* kg_ = k_h  + (size_t)h * NTOK * DIM_HEAD + (size_t)j0 * DIM_HEAD;
    const _Float16* vg  = vT_h + (size_t)h * DIM_HEAD * NTOK + j0;
    const int krow = tid >> 3, kc8 = tid & 7;       // K staging (64 rows x 8B)
    const int vrow = tid >> 4, vseg = tid & 15;     // V^T staging (32 rows x 8B)

    uint2 kreg, vreg;
    kreg = ((const uint2*)kg_)[tid];
    vreg = *(const uint2*)(vg + (size_t)vrow * NTOK + vseg * 4);
    *(uint2*)&lk[0][krow * KPAD + kc8 * 4] = kreg;
    *(uint2*)&lvt[0][vrow * VPAD + vseg * 4] = vreg;
    kreg = ((const uint2*)(kg_ + (size_t)TJ * DIM_HEAD))[tid];
    vreg = *(const uint2*)(vg + (size_t)vrow * NTOK + TJ + vseg * 4);
    __syncthreads();

    const int NT = jlen / TJ;     // 8
    for (int t = 0; t < NT; ++t) {
        const int cur = t & 1;
        if (t + 1 < NT) {
            *(uint2*)&lk[cur ^ 1][krow * KPAD + kc8 * 4] = kreg;
            *(uint2*)&lvt[cur ^ 1][vrow * VPAD + vseg * 4] = vreg;
            if (t + 2 < NT) {
                kreg = ((const uint2*)(kg_ + (size_t)(t + 2) * TJ * DIM_HEAD))[tid];
                vreg = *(const uint2*)(vg + (size_t)vrow * NTOK + (t + 2) * TJ + vseg * 4);
            }
        }
        // ---- QK^T swapped (32x32): sc D[key_local][q=la32] ----
        f32x16 z;
        #pragma unroll
        for (int r = 0; r < 16; ++r) z[r] = 0.f;
        const half8 ak00 = *(const half8*)&lk[cur][(la32     ) * KPAD +      hi * 8];
        const half8 ak01 = *(const half8*)&lk[cur][(la32     ) * KPAD + 16 + hi * 8];
        const half8 ak10 = *(const half8*)&lk[cur][(32 + la32) * KPAD +      hi * 8];
        const half8 ak11 = *(const half8*)&lk[cur][(32 + la32) * KPAD + 16 + hi * 8];
        f32x16 sc0 = __builtin_amdgcn_mfma_f32_32x32x16_f16(ak00, bq0, z, 0, 0, 0);
        sc0        = __builtin_amdgcn_mfma_f32_32x32x16_f16(ak01, bq1, sc0, 0, 0, 0);
        f32x16 sc1 = __builtin_amdgcn_mfma_f32_32x32x16_f16(ak10, bq0, z, 0, 0, 0);
        sc1        = __builtin_amdgcn_mfma_f32_32x32x16_f16(ak11, bq1, sc1, 0, 0, 0);
        // ---- max over 32 in-lane regs + 1 cross-replica shfl ----
        float tm = sc0[0];
        #pragma unroll
        for (int r = 1; r < 16; ++r) tm = fmaxf(tm, sc0[r]);
        #pragma unroll
        for (int r = 0; r < 16; ++r) tm = fmaxf(tm, sc1[r]);
        tm = fmaxf(tm, __shfl_xor(tm, 32));
        const float mn   = fmaxf(m, tm);
        const float corr = __expf(m - mn);
        m = mn;
        l *= corr;
        #pragma unroll
        for (int r = 0; r < 16; ++r) acc[r] *= corr;
        // ---- probabilities (stay in registers) ----
        float p0[16], p1[16];
        float ps = 0.f;
        #pragma unroll
        for (int r = 0; r < 16; ++r) { p0[r] = __expf(sc0[r] - mn); ps += p0[r]; }
        #pragma unroll
        for (int r = 0; r < 16; ++r) { p1[r] = __expf(sc1[r] - mn); ps += p1[r]; }
        l += ps;
        // ---- PV: per 16-key chunk, build P B-frag in-register and MFMA --------
        // frag(c): halves = P[q][16c+8hi+j]; after swap(A,C),swap(B,D) the words
        // {A,B,C,D} are correct for BOTH hi halves.
        #define DO_CHUNK(P, C2, CIDX)                                              \
        {                                                                          \
            union { fp16x2 hh; unsigned u; } A_, B_, C_, D_;                       \
            A_.hh = __builtin_amdgcn_cvt_pkrtz(P[8*(C2)+0], P[8*(C2)+1]);          \
            B_.hh = __builtin_amdgcn_cvt_pkrtz(P[8*(C2)+2], P[8*(C2)+3]);          \
            C_.hh = __builtin_amdgcn_cvt_pkrtz(P[8*(C2)+4], P[8*(C2)+5]);          \
            D_.hh = __builtin_amdgcn_cvt_pkrtz(P[8*(C2)+6], P[8*(C2)+7]);          \
            asm("v_permlane32_swap_b32 %0, %1" : "+v"(A_.u), "+v"(C_.u));          \
            asm("v_permlane32_swap_b32 %0, %1" : "+v"(B_.u), "+v"(D_.u));          \
            union { unsigned u[4]; half8 v; } F_;                                  \
            F_.u[0] = A_.u; F_.u[1] = B_.u; F_.u[2] = C_.u; F_.u[3] = D_.u;        \
            const half8 av = *(const half8*)&lvt[cur][la32 * VPAD + (CIDX) * 16 + hi * 8]; \
            acc = __builtin_amdgcn_mfma_f32_32x32x16_f16(av, F_.v, acc, 0, 0, 0);  \
        }
        DO_CHUNK(p0, 0, 0)
        DO_CHUNK(p0, 1, 1)
        DO_CHUNK(p1, 0, 2)
        DO_CHUNK(p1, 1, 3)
        #undef DO_CHUNK
        __syncthreads();
    }
    // ---- epilogue: combine replicas' l; store partial state ----
    float lt = l + __shfl_xor(l, 32);
    const size_t pbase = (size_t)(h * JS + s) * NTOK + qbase;
    if (hi == 0) {
        pm[pbase + la32] = m;
        pl[pbase + la32] = lt;
    }
    // acc[reg] holds out[d = (reg&3)+8*(reg>>2)+4*hi][q = la32]
    #pragma unroll
    for (int g = 0; g < 4; ++g) {
        union { fp16x2 hh; unsigned u; } u0, u1;
        u0.hh = __builtin_amdgcn_cvt_pkrtz(acc[4*g],     acc[4*g + 1]);
        u1.hh = __builtin_amdgcn_cvt_pkrtz(acc[4*g + 2], acc[4*g + 3]);
        uint2 st; st.x = u0.u; st.y = u1.u;
        *(uint2*)(pacc + (pbase + la32) * DIM_HEAD + 8 * g + 4 * hi) = st;
    }
}

// -------------------- 5. Combine partials (JS=8, fp16 pacc) -> attT fp16 -------
__global__ void attn_combine(const float* __restrict__ pm, const float* __restrict__ pl,
                             const _Float16* __restrict__ pacc, _Float16* __restrict__ attT) {
    const int i = blockIdx.x * blockDim.x + threadIdx.x;   // 0..4095
    const int h = blockIdx.y;
    float mv[JS], lv[JS];
    float mM = -1e30f;
    #pragma unroll
    for (int s = 0; s < JS; ++s) {
        const size_t pidx = ((size_t)(h * JS + s) * NTOK + i);
        mv[s] = pm[pidx];
        lv[s] = pl[pidx];
        mM = fmaxf(mM, mv[s]);
    }
    float wv[JS];
    float denom = 0.f;
    #pragma unroll
    for (int s = 0; s < JS; ++s) {
        wv[s] = __expf(mv[s] - mM);
        denom += lv[s] * wv[s];
    }
    const float inv = 1.f / denom;
    __attribute__((aligned(16))) _Float16 hv[DIM_HEAD];
    #pragma unroll
    for (int d0 = 0; d0 < DIM_HEAD; d0 += 4) {
        float o0 = 0.f, o1 = 0.f, o2 = 0.f, o3 = 0.f;
        #pragma unroll
        for (int s = 0; s < JS; ++s) {
            const size_t pidx = ((size_t)(h * JS + s) * NTOK + i);
            const half4 a = *(const half4*)(pacc + pidx * DIM_HEAD + d0);
            o0 = fmaf((float)a.x, wv[s], o0);
            o1 = fmaf((float)a.y, wv[s], o1);
            o2 = fmaf((float)a.z, wv[s], o2);
            o3 = fmaf((float)a.w, wv[s], o3);
        }
        hv[d0]     = (_Float16)(o0 * inv);
        hv[d0 + 1] = (_Float16)(o1 * inv);
        hv[d0 + 2] = (_Float16)(o2 * inv);
        hv[d0 + 3] = (_Float16)(o3 * inv);
    }
    _Float16* dst = attT + (size_t)i * CCH + h * DIM_HEAD;   // 64 B contiguous
    #pragma unroll
    for (int q = 0; q < 4; ++q) ((uint4*)dst)[q] = ((const uint4*)hv)[q];
}

// -------------------- 6. Output projection via MFMA + bias + residual ----------
__global__ __launch_bounds__(256)
void out_mfma(const _Float16* __restrict__ wouth, const float* __restrict__ bo,
              const _Float16* __restrict__ attT, const float* __restrict__ x,
              float* __restrict__ out) {
    const int tid = threadIdx.x, w = tid >> 6, lane = tid & 63;
    const int la = lane & 15, lg = lane >> 4;
    const int jb = blockIdx.x * 64 + w * 16;
    const int ob = blockIdx.y * 16;
    const _Float16* arow = wouth + (size_t)(ob + la) * CCH;   // D row = o
    const _Float16* brow = attT  + (size_t)(jb + la) * CCH;   // D col = j
    f32x4 acc = {0.f, 0.f, 0.f, 0.f};
    #pragma unroll
    for (int kk = 0; kk < CCH; kk += 32) {
        const half8 a = *(const half8*)(arow + kk + lg * 8);
        const half8 b = *(const half8*)(brow + kk + lg * 8);
        acc = __builtin_amdgcn_mfma_f32_16x16x32_f16(a, b, acc, 0, 0, 0);
    }
    const float4 b4 = *(const float4*)(bo + ob + lg * 4);
    const float bb[4] = {b4.x, b4.y, b4.z, b4.w};
    #pragma unroll
    for (int r = 0; r < 4; ++r) {
        const int o = ob + lg * 4 + r;
        const size_t idx = (size_t)o * NTOK + jb + la;
        out[idx] = acc[r] + bb[r] + x[idx];
    }
}

extern "C" void kernel_launch(void* const* d_in, const int* in_sizes, int n_in,
                              void* d_out, int out_size, void* d_ws, size_t ws_size,
                              hipStream_t stream) {
    const float* x     = (const float*)d_in[0];
    const float* gamma = (const float*)d_in[1];
    const float* beta  = (const float*)d_in[2];
    const float* w_qkv = (const float*)d_in[3];
    const float* b_qkv = (const float*)d_in[4];
    const float* w_out = (const float*)d_in[5];
    const float* b_out = (const float*)d_in[6];
    float* out = (float*)d_out;

    float* ws   = (float*)d_ws;
    float* part = ws;                           // 512
    float* b2   = part + 512;                   // 768
    float* pm   = b2 + 768;                     // 8*8*4096 = 262144
    float* pl   = pm + 262144;                  // 262144
    _Float16* pacc = (_Float16*)(pl + 262144);  // 8*8*4096*32 halves (16.8 MB)
    float* fend = pl + 262144 + 4194304;        // pacc = 4194304 floats worth
    _Float16* q_h   = (_Float16*)fend;          // 1048576 halves each
    _Float16* k_h   = q_h  + 1048576;
    _Float16* vT_h  = k_h  + 1048576;
    _Float16* xT    = vT_h + 1048576;           // 1048576
    _Float16* w2h   = xT   + 1048576;           // 196608
    _Float16* wouth = w2h  + 196608;            // 65536
    _Float16* attT  = wouth + 65536;            // 1048576
    // total ~31 MB (ws proven >= 92 MB in round 2)

    {
        dim3 g(GN_SPLIT, GROUPS);
        gn_stats_partial<<<g, 256, 0, stream>>>(x, part);
    }
    fold_qkv<<<5 * CCH, 256, 0, stream>>>(w_qkv, b_qkv, gamma, beta, part, w_out, x,
                                          w2h, b2, wouth, xT);
    {
        dim3 g(NTOK / 64, 3 * CCH / 16);
        qkv_mfma<<<g, 256, 0, stream>>>(w2h, b2, xT, q_h, k_h, vT_h);
    }
    {
        dim3 g(NTOK / 256, HEADS, JS);
        attn_mfma<<<g, 512, 0, stream>>>(q_h, k_h, vT_h, pm, pl, pacc);
    }
    {
        dim3 g(NTOK / 256, HEADS);
        attn_combine<<<g, 256, 0, stream>>>(pm, pl, pacc, attT);
    }
    {
        dim3 g(NTOK / 64, CCH / 16);
        out_mfma<<<g, 256, 0, stream>>>(wouth, b_out, attT, x, out);
    }
}

// Round 20
// 79.984 us; speedup vs baseline: 1.3507x; 1.1120x over previous
//
#include <hip/hip_runtime.h>
#include <hip/hip_bf16.h>

#define HEADS 8
#define DIM_HEAD 32
#define GROUPS 8
#define CCH 256            // channels
#define NTOK 4096          // d*h*w = 16^3
#define EPS 1e-5f
#define GN_SPLIT 32
#define JS 8               // attention j-split

typedef _Float16 half8 __attribute__((ext_vector_type(8)));
typedef _Float16 half4 __attribute__((ext_vector_type(4)));
typedef __fp16   fp16x2 __attribute__((ext_vector_type(2)));   // cvt_pkrtz return type
typedef float f32x4 __attribute__((ext_vector_type(4)));
typedef float f32x16 __attribute__((ext_vector_type(16)));

// -------------------- 1. GroupNorm partial stats --------------------
__global__ void gn_stats_partial(const float* __restrict__ x, float* __restrict__ part) {
    const int g  = blockIdx.y;
    const int sp = blockIdx.x;
    const int M = (CCH / GROUPS) * NTOK;        // 131072 contiguous floats per group
    const int chunk = M / GN_SPLIT;             // 4096
    const float4* p = (const float4*)(x + (size_t)g * M + (size_t)sp * chunk);
    float s = 0.f, ss = 0.f;
    for (int i = threadIdx.x; i < chunk / 4; i += blockDim.x) {
        float4 v = p[i];
        s  += v.x + v.y + v.z + v.w;
        ss += v.x*v.x + v.y*v.y + v.z*v.z + v.w*v.w;
    }
    #pragma unroll
    for (int off = 32; off; off >>= 1) {
        s  += __shfl_down(s,  off);
        ss += __shfl_down(ss, off);
    }
    __shared__ float sh0[8], sh1[8];
    const int wave = threadIdx.x >> 6, lane = threadIdx.x & 63;
    if (lane == 0) { sh0[wave] = s; sh1[wave] = ss; }
    __syncthreads();
    if (threadIdx.x == 0) {
        float S = 0.f, SS = 0.f;
        const int nw = blockDim.x >> 6;
        for (int w = 0; w < nw; ++w) { S += sh0[w]; SS += sh1[w]; }
        part[(g * GN_SPLIT + sp) * 2]     = S;
        part[(g * GN_SPLIT + sp) * 2 + 1] = SS;
    }
}

// -------------------- 2. Fold GN into QKV weights + w_out fp16 + x transpose ----
__global__ __launch_bounds__(256)
void fold_qkv(const float* __restrict__ w, const float* __restrict__ b,
              const float* __restrict__ gamma, const float* __restrict__ beta,
              const float* __restrict__ part, const float* __restrict__ w_out,
              const float* __restrict__ x,
              _Float16* __restrict__ w2h, float* __restrict__ b2,
              _Float16* __restrict__ wouth, _Float16* __restrict__ xT) {
    const int o = blockIdx.x;
    const int c = threadIdx.x;          // 0..255
    if (o >= 4 * CCH) {                 // ---- transpose tile ----
        const int t  = o - 4 * CCH;     // 0..255
        const int jb = (t & 63) * 64;
        const int cb = (t >> 6) * 64;
        __shared__ float tile[64][65];
        const int tj = threadIdx.x & 63, tc = threadIdx.x >> 6;
        #pragma unroll
        for (int cc = 0; cc < 64; cc += 4)
            tile[cc + tc][tj] = x[(size_t)(cb + cc + tc) * NTOK + jb + tj];
        __syncthreads();
        const int wc = threadIdx.x & 63, wj = threadIdx.x >> 6;
        #pragma unroll
        for (int jj = 0; jj < 64; jj += 4)
            xT[(size_t)(jb + jj + wj) * CCH + cb + wc] = (_Float16)tile[wc][jj + wj];
        return;
    }
    if (o >= 3 * CCH) {                 // ---- w_out convert ----
        const int oo = o - 3 * CCH;
        wouth[(size_t)oo * CCH + c] = (_Float16)w_out[(size_t)oo * CCH + c];
        return;
    }
    __shared__ float smean[GROUPS], srstd[GROUPS];
    if (c < GROUPS) {
        float s = 0.f, ss = 0.f;
        #pragma unroll
        for (int i = 0; i < GN_SPLIT; ++i) {
            s  += part[(c * GN_SPLIT + i) * 2];
            ss += part[(c * GN_SPLIT + i) * 2 + 1];
        }
        const float M = (float)((CCH / GROUPS) * NTOK);
        const float mean = s / M;
        const float var  = ss / M - mean * mean;
        smean[c] = mean;
        srstd[c] = rsqrtf(var + EPS);
    }
    __syncthreads();
    const int g = c >> 5;
    const float sc = gamma[c] * srstd[g];
    const float sh = beta[c] - smean[g] * sc;
    const float wv = w[(size_t)o * CCH + c];
    w2h[(size_t)o * CCH + c] = (_Float16)(wv * sc);
    float t = wv * sh;
    #pragma unroll
    for (int off = 32; off; off >>= 1) t += __shfl_down(t, off);
    __shared__ float shred[4];
    const int wave = threadIdx.x >> 6, lane = threadIdx.x & 63;
    if (lane == 0) shred[wave] = t;
    __syncthreads();
    if (threadIdx.x == 0)
        b2[o] = b[o] + shred[0] + shred[1] + shred[2] + shred[3];
}

// -------------------- 3. QKV GEMM via MFMA, 32 outputs/wave --------------------
// R19: each y-block streamed the whole xT panel (48 blocks x 8 MB = 384 MB L2
// traffic) and ran one serial 8-deep MFMA chain. 32 outputs/wave: one A-frag
// feeds TWO independent accumulator chains -> xT reads halve (y-grid 48->24)
// and the MFMA chains pipeline.
__global__ __launch_bounds__(256)
void qkv_mfma(const _Float16* __restrict__ w2h, const float* __restrict__ b2,
              const _Float16* __restrict__ xT,
              _Float16* __restrict__ q_h, _Float16* __restrict__ k_h,
              _Float16* __restrict__ vT_h) {
    const int tid = threadIdx.x, w = tid >> 6, lane = tid & 63;
    const int la = lane & 15, lg = lane >> 4;
    const int jb = blockIdx.x * 64 + w * 16;   // wave's 16 tokens
    const int ob = blockIdx.y * 32;            // 32 output rows (32-aligned: same part/h)
    const int part = ob >> 8;
    f32x4 acc0 = {0.f, 0.f, 0.f, 0.f};
    f32x4 acc1 = {0.f, 0.f, 0.f, 0.f};
    if (part < 2) {
        // A = xT token rows (D row = j), B = w2h o-rows (D col = o)
        const _Float16* arow  = xT  + (size_t)(jb + la) * CCH;
        const _Float16* brow0 = w2h + (size_t)(ob + la) * CCH;
        const _Float16* brow1 = w2h + (size_t)(ob + 16 + la) * CCH;
        #pragma unroll
        for (int kk = 0; kk < CCH; kk += 32) {
            const half8 a  = *(const half8*)(arow  + kk + lg * 8);
            const half8 b0 = *(const half8*)(brow0 + kk + lg * 8);
            const half8 b1 = *(const half8*)(brow1 + kk + lg * 8);
            acc0 = __builtin_amdgcn_mfma_f32_16x16x32_f16(a, b0, acc0, 0, 0, 0);
            acc1 = __builtin_amdgcn_mfma_f32_16x16x32_f16(a, b1, acc1, 0, 0, 0);
        }
        const int h = (ob & 255) >> 5;
        const float bias0 = b2[ob + la];
        const float bias1 = b2[ob + 16 + la];
        _Float16* dst = (part == 0) ? q_h : k_h;
        const float scl = (part == 0) ? 0.17677669529663687f : 1.0f;  // 32^-0.5
        #pragma unroll
        for (int r = 0; r < 4; ++r) {
            const int j = jb + lg * 4 + r;
            _Float16* base = dst + ((size_t)h * NTOK + j) * DIM_HEAD;
            base[la]      = (_Float16)((acc0[r] + bias0) * scl);
            base[16 + la] = (_Float16)((acc1[r] + bias1) * scl);
        }
    } else {
        // A = w2h o-rows (D row = o=d), B = xT token rows (D col = j)
        const _Float16* arow0 = w2h + (size_t)(ob + la) * CCH;
        const _Float16* arow1 = w2h + (size_t)(ob + 16 + la) * CCH;
        const _Float16* brow  = xT  + (size_t)(jb + la) * CCH;
        #pragma unroll
        for (int kk = 0; kk < CCH; kk += 32) {
            const half8 a0 = *(const half8*)(arow0 + kk + lg * 8);
            const half8 a1 = *(const half8*)(arow1 + kk + lg * 8);
            const half8 b  = *(const half8*)(brow  + kk + lg * 8);
            acc0 = __builtin_amdgcn_mfma_f32_16x16x32_f16(a0, b, acc0, 0, 0, 0);
            acc1 = __builtin_amdgcn_mfma_f32_16x16x32_f16(a1, b, acc1, 0, 0, 0);
        }
        const int h = (ob & 255) >> 5;
        const float4 b40 = *(const float4*)(b2 + ob + lg * 4);
        const float4 b41 = *(const float4*)(b2 + ob + 16 + lg * 4);
        const float bb0[4] = {b40.x, b40.y, b40.z, b40.w};
        const float bb1[4] = {b41.x, b41.y, b41.z, b41.w};
        #pragma unroll
        for (int r = 0; r < 4; ++r) {
            const int d0 = lg * 4 + r;
            vT_h[((size_t)h * DIM_HEAD + d0     ) * NTOK + jb + la] = (_Float16)(acc0[r] + bb0[r]);
            vT_h[((size_t)h * DIM_HEAD + d0 + 16) * NTOK + jb + la] = (_Float16)(acc1[r] + bb1[r]);
        }
    }
}

// -------------------- 4. Flash attention: 32x32 MFMA, P in registers (T12) -----
#define TJ 64
#define KPAD 36
#define VPAD 72
__global__ __launch_bounds__(512)
void attn_mfma(const _Float16* __restrict__ q_h, const _Float16* __restrict__ k_h,
               const _Float16* __restrict__ vT_h,
               float* __restrict__ pm, float* __restrict__ pl,
               _Float16* __restrict__ pacc) {
    const int tid = threadIdx.x;                 // 0..511
    const int w = tid >> 6, lane = tid & 63;
    const int la32 = lane & 31, hi = lane >> 5;
    const int h = blockIdx.y;
    const int s = blockIdx.z;
    const int qbase = blockIdx.x * 256 + w * 32;
    const int jlen = NTOK / JS;          // 512
    const int j0 = s * jlen;

    __shared__ _Float16 lk [2][TJ * KPAD];           // 2 x 4.5 KB (64 key rows)
    __shared__ _Float16 lvt[2][DIM_HEAD * VPAD];     // 2 x 4.5 KB (32 d rows)

    // Q B-fragments: lane holds Q row q=la32, d = c16*16 + hi*8 .. +7
    const _Float16* qrow = q_h + ((size_t)h * NTOK + qbase + la32) * DIM_HEAD;
    const half8 bq0 = *(const half8*)(qrow + hi * 8);
    const half8 bq1 = *(const half8*)(qrow + 16 + hi * 8);

    f32x16 acc;
    #pragma unroll
    for (int r = 0; r < 16; ++r) acc[r] = 0.f;
    float m = -1e30f, l = 0.f;           // per-lane: query la32 (replicated in hi)

    const _Float16* kg_ = k_h  + (size_t)h * NTOK * DIM_HEAD + (size_t)j0 * DIM_HEAD;
    const _Float16* vg  = vT_h + (size_t)h * DIM_HEAD * NTOK + j0;
    const int krow = tid >> 3, kc8 = tid & 7;       // K staging (64 rows x 8B)
    const int vrow = tid >> 4, vseg = tid & 15;     // V^T staging (32 rows x 8B)

    uint2 kreg, vreg;
    kreg = ((const uint2*)kg_)[tid];
    vreg = *(const uint2*)(vg + (size_t)vrow * NTOK + vseg * 4);
    *(uint2*)&lk[0][krow * KPAD + kc8 * 4] = kreg;
    *(uint2*)&lvt[0][vrow * VPAD + vseg * 4] = vreg;
    kreg = ((const uint2*)(kg_ + (size_t)TJ * DIM_HEAD))[tid];
    vreg = *(const uint2*)(vg + (size_t)vrow * NTOK + TJ + vseg * 4);
    __syncthreads();

    const int NT = jlen / TJ;     // 8
    for (int t = 0; t < NT; ++t) {
        const int cur = t & 1;
        if (t + 1 < NT) {
            *(uint2*)&lk[cur ^ 1][krow * KPAD + kc8 * 4] = kreg;
            *(uint2*)&lvt[cur ^ 1][vrow * VPAD + vseg * 4] = vreg;
            if (t + 2 < NT) {
                kreg = ((const uint2*)(kg_ + (size_t)(t + 2) * TJ * DIM_HEAD))[tid];
                vreg = *(const uint2*)(vg + (size_t)vrow * NTOK + (t + 2) * TJ + vseg * 4);
            }
        }
        // ---- QK^T swapped (32x32): sc D[key_local][q=la32] ----
        f32x16 z;
        #pragma unroll
        for (int r = 0; r < 16; ++r) z[r] = 0.f;
        const half8 ak00 = *(const half8*)&lk[cur][(la32     ) * KPAD +      hi * 8];
        const half8 ak01 = *(const half8*)&lk[cur][(la32     ) * KPAD + 16 + hi * 8];
        const half8 ak10 = *(const half8*)&lk[cur][(32 + la32) * KPAD +      hi * 8];
        const half8 ak11 = *(const half8*)&lk[cur][(32 + la32) * KPAD + 16 + hi * 8];
        f32x16 sc0 = __builtin_amdgcn_mfma_f32_32x32x16_f16(ak00, bq0, z, 0, 0, 0);
        sc0        = __builtin_amdgcn_mfma_f32_32x32x16_f16(ak01, bq1, sc0, 0, 0, 0);
        f32x16 sc1 = __builtin_amdgcn_mfma_f32_32x32x16_f16(ak10, bq0, z, 0, 0, 0);
        sc1        = __builtin_amdgcn_mfma_f32_32x32x16_f16(ak11, bq1, sc1, 0, 0, 0);
        // ---- max over 32 in-lane regs + 1 cross-replica shfl ----
        float tm = sc0[0];
        #pragma unroll
        for (int r = 1; r < 16; ++r) tm = fmaxf(tm, sc0[r]);
        #pragma unroll
        for (int r = 0; r < 16; ++r) tm = fmaxf(tm, sc1[r]);
        tm = fmaxf(tm, __shfl_xor(tm, 32));
        const float mn   = fmaxf(m, tm);
        const float corr = __expf(m - mn);
        m = mn;
        l *= corr;
        #pragma unroll
        for (int r = 0; r < 16; ++r) acc[r] *= corr;
        // ---- probabilities (stay in registers) ----
        float p0[16], p1[16];
        float ps = 0.f;
        #pragma unroll
        for (int r = 0; r < 16; ++r) { p0[r] = __expf(sc0[r] - mn); ps += p0[r]; }
        #pragma unroll
        for (int r = 0; r < 16; ++r) { p1[r] = __expf(sc1[r] - mn); ps += p1[r]; }
        l += ps;
        // ---- PV: per 16-key chunk, build P B-frag in-register and MFMA --------
        #define DO_CHUNK(P, C2, CIDX)                                              \
        {                                                                          \
            union { fp16x2 hh; unsigned u; } A_, B_, C_, D_;                       \
            A_.hh = __builtin_amdgcn_cvt_pkrtz(P[8*(C2)+0], P[8*(C2)+1]);          \
            B_.hh = __builtin_amdgcn_cvt_pkrtz(P[8*(C2)+2], P[8*(C2)+3]);          \
            C_.hh = __builtin_amdgcn_cvt_pkrtz(P[8*(C2)+4], P[8*(C2)+5]);          \
            D_.hh = __builtin_amdgcn_cvt_pkrtz(P[8*(C2)+6], P[8*(C2)+7]);          \
            asm("v_permlane32_swap_b32 %0, %1" : "+v"(A_.u), "+v"(C_.u));          \
            asm("v_permlane32_swap_b32 %0, %1" : "+v"(B_.u), "+v"(D_.u));          \
            union { unsigned u[4]; half8 v; } F_;                                  \
            F_.u[0] = A_.u; F_.u[1] = B_.u; F_.u[2] = C_.u; F_.u[3] = D_.u;        \
            const half8 av = *(const half8*)&lvt[cur][la32 * VPAD + (CIDX) * 16 + hi * 8]; \
            acc = __builtin_amdgcn_mfma_f32_32x32x16_f16(av, F_.v, acc, 0, 0, 0);  \
        }
        DO_CHUNK(p0, 0, 0)
        DO_CHUNK(p0, 1, 1)
        DO_CHUNK(p1, 0, 2)
        DO_CHUNK(p1, 1, 3)
        #undef DO_CHUNK
        __syncthreads();
    }
    // ---- epilogue: combine replicas' l; store partial state ----
    float lt = l + __shfl_xor(l, 32);
    const size_t pbase = (size_t)(h * JS + s) * NTOK + qbase;
    if (hi == 0) {
        pm[pbase + la32] = m;
        pl[pbase + la32] = lt;
    }
    // acc[reg] holds out[d = (reg&3)+8*(reg>>2)+4*hi][q = la32]
    #pragma unroll
    for (int g = 0; g < 4; ++g) {
        union { fp16x2 hh; unsigned u; } u0, u1;
        u0.hh = __builtin_amdgcn_cvt_pkrtz(acc[4*g],     acc[4*g + 1]);
        u1.hh = __builtin_amdgcn_cvt_pkrtz(acc[4*g + 2], acc[4*g + 3]);
        uint2 st; st.x = u0.u; st.y = u1.u;
        *(uint2*)(pacc + (pbase + la32) * DIM_HEAD + 8 * g + 4 * hi) = st;
    }
}

// -------------------- 5. Combine partials (JS=8, fp16 pacc) -> attT fp16 -------
__global__ void attn_combine(const float* __restrict__ pm, const float* __restrict__ pl,
                             const _Float16* __restrict__ pacc, _Float16* __restrict__ attT) {
    const int i = blockIdx.x * blockDim.x + threadIdx.x;   // 0..4095
    const int h = blockIdx.y;
    float mv[JS], lv[JS];
    float mM = -1e30f;
    #pragma unroll
    for (int s = 0; s < JS; ++s) {
        const size_t pidx = ((size_t)(h * JS + s) * NTOK + i);
        mv[s] = pm[pidx];
        lv[s] = pl[pidx];
        mM = fmaxf(mM, mv[s]);
    }
    float wv[JS];
    float denom = 0.f;
    #pragma unroll
    for (int s = 0; s < JS; ++s) {
        wv[s] = __expf(mv[s] - mM);
        denom += lv[s] * wv[s];
    }
    const float inv = 1.f / denom;
    __attribute__((aligned(16))) _Float16 hv[DIM_HEAD];
    #pragma unroll
    for (int d0 = 0; d0 < DIM_HEAD; d0 += 4) {
        float o0 = 0.f, o1 = 0.f, o2 = 0.f, o3 = 0.f;
        #pragma unroll
        for (int s = 0; s < JS; ++s) {
            const size_t pidx = ((size_t)(h * JS + s) * NTOK + i);
            const half4 a = *(const half4*)(pacc + pidx * DIM_HEAD + d0);
            o0 = fmaf((float)a.x, wv[s], o0);
            o1 = fmaf((float)a.y, wv[s], o1);
            o2 = fmaf((float)a.z, wv[s], o2);
            o3 = fmaf((float)a.w, wv[s], o3);
        }
        hv[d0]     = (_Float16)(o0 * inv);
        hv[d0 + 1] = (_Float16)(o1 * inv);
        hv[d0 + 2] = (_Float16)(o2 * inv);
        hv[d0 + 3] = (_Float16)(o3 * inv);
    }
    _Float16* dst = attT + (size_t)i * CCH + h * DIM_HEAD;   // 64 B contiguous
    #pragma unroll
    for (int q = 0; q < 4; ++q) ((uint4*)dst)[q] = ((const uint4*)hv)[q];
}

// -------------------- 6. Output projection via MFMA, 32 outputs/wave -----------
__global__ __launch_bounds__(256)
void out_mfma(const _Float16* __restrict__ wouth, const float* __restrict__ bo,
              const _Float16* __restrict__ attT, const float* __restrict__ x,
              float* __restrict__ out) {
    const int tid = threadIdx.x, w = tid >> 6, lane = tid & 63;
    const int la = lane & 15, lg = lane >> 4;
    const int jb = blockIdx.x * 64 + w * 16;
    const int ob = blockIdx.y * 32;
    const _Float16* arow0 = wouth + (size_t)(ob + la) * CCH;        // D row = o
    const _Float16* arow1 = wouth + (size_t)(ob + 16 + la) * CCH;
    const _Float16* brow  = attT  + (size_t)(jb + la) * CCH;        // D col = j
    f32x4 acc0 = {0.f, 0.f, 0.f, 0.f};
    f32x4 acc1 = {0.f, 0.f, 0.f, 0.f};
    #pragma unroll
    for (int kk = 0; kk < CCH; kk += 32) {
        const half8 a0 = *(const half8*)(arow0 + kk + lg * 8);
        const half8 a1 = *(const half8*)(arow1 + kk + lg * 8);
        const half8 b  = *(const half8*)(brow  + kk + lg * 8);
        acc0 = __builtin_amdgcn_mfma_f32_16x16x32_f16(a0, b, acc0, 0, 0, 0);
        acc1 = __builtin_amdgcn_mfma_f32_16x16x32_f16(a1, b, acc1, 0, 0, 0);
    }
    const float4 b40 = *(const float4*)(bo + ob + lg * 4);
    const float4 b41 = *(const float4*)(bo + ob + 16 + lg * 4);
    const float bb0[4] = {b40.x, b40.y, b40.z, b40.w};
    const float bb1[4] = {b41.x, b41.y, b41.z, b41.w};
    #pragma unroll
    for (int r = 0; r < 4; ++r) {
        const int o0 = ob + lg * 4 + r;
        const size_t idx0 = (size_t)o0 * NTOK + jb + la;
        out[idx0] = acc0[r] + bb0[r] + x[idx0];
        const int o1 = ob + 16 + lg * 4 + r;
        const size_t idx1 = (size_t)o1 * NTOK + jb + la;
        out[idx1] = acc1[r] + bb1[r] + x[idx1];
    }
}

extern "C" void kernel_launch(void* const* d_in, const int* in_sizes, int n_in,
                              void* d_out, int out_size, void* d_ws, size_t ws_size,
                              hipStream_t stream) {
    const float* x     = (const float*)d_in[0];
    const float* gamma = (const float*)d_in[1];
    const float* beta  = (const float*)d_in[2];
    const float* w_qkv = (const float*)d_in[3];
    const float* b_qkv = (const float*)d_in[4];
    const float* w_out = (const float*)d_in[5];
    const float* b_out = (const float*)d_in[6];
    float* out = (float*)d_out;

    float* ws   = (float*)d_ws;
    float* part = ws;                           // 512
    float* b2   = part + 512;                   // 768
    float* pm   = b2 + 768;                     // 8*8*4096 = 262144
    float* pl   = pm + 262144;                  // 262144
    _Float16* pacc = (_Float16*)(pl + 262144);  // 8*8*4096*32 halves (16.8 MB)
    float* fend = pl + 262144 + 4194304;        // pacc = 4194304 floats worth
    _Float16* q_h   = (_Float16*)fend;          // 1048576 halves each
    _Float16* k_h   = q_h  + 1048576;
    _Float16* vT_h  = k_h  + 1048576;
    _Float16* xT    = vT_h + 1048576;           // 1048576
    _Float16* w2h   = xT   + 1048576;           // 196608
    _Float16* wouth = w2h  + 196608;            // 65536
    _Float16* attT  = wouth + 65536;            // 1048576
    // total ~31 MB (ws proven >= 92 MB in round 2)

    {
        dim3 g(GN_SPLIT, GROUPS);
        gn_stats_partial<<<g, 256, 0, stream>>>(x, part);
    }
    fold_qkv<<<5 * CCH, 256, 0, stream>>>(w_qkv, b_qkv, gamma, beta, part, w_out, x,
                                          w2h, b2, wouth, xT);
    {
        dim3 g(NTOK / 64, 3 * CCH / 32);
        qkv_mfma<<<g, 256, 0, stream>>>(w2h, b2, xT, q_h, k_h, vT_h);
    }
    {
        dim3 g(NTOK / 256, HEADS, JS);
        attn_mfma<<<g, 512, 0, stream>>>(q_h, k_h, vT_h, pm, pl, pacc);
    }
    {
        dim3 g(NTOK / 256, HEADS);
        attn_combine<<<g, 256, 0, stream>>>(pm, pl, pacc, attT);
    }
    {
        dim3 g(NTOK / 64, CCH / 32);
        out_mfma<<<g, 256, 0, stream>>>(wouth, b_out, attT, x, out);
    }
}

// Round 21
// 78.206 us; speedup vs baseline: 1.3814x; 1.0227x over previous
//
#include <hip/hip_runtime.h>
#include <hip/hip_bf16.h>

#define HEADS 8
#define DIM_HEAD 32
#define GROUPS 8
#define CCH 256            // channels
#define NTOK 4096          // d*h*w = 16^3
#define EPS 1e-5f
#define GN_SPLIT 32
#define JS 4               // attention j-split (R20: attn VGPR caps waves/SIMD ~3;
                           // JS=4's 16 waves/CU already saturates -> halve split-K cost)

typedef _Float16 half8 __attribute__((ext_vector_type(8)));
typedef _Float16 half4 __attribute__((ext_vector_type(4)));
typedef __fp16   fp16x2 __attribute__((ext_vector_type(2)));   // cvt_pkrtz return type
typedef float f32x4 __attribute__((ext_vector_type(4)));
typedef float f32x16 __attribute__((ext_vector_type(16)));

// -------------------- 1. GroupNorm partial stats --------------------
__global__ void gn_stats_partial(const float* __restrict__ x, float* __restrict__ part) {
    const int g  = blockIdx.y;
    const int sp = blockIdx.x;
    const int M = (CCH / GROUPS) * NTOK;        // 131072 contiguous floats per group
    const int chunk = M / GN_SPLIT;             // 4096
    const float4* p = (const float4*)(x + (size_t)g * M + (size_t)sp * chunk);
    float s = 0.f, ss = 0.f;
    for (int i = threadIdx.x; i < chunk / 4; i += blockDim.x) {
        float4 v = p[i];
        s  += v.x + v.y + v.z + v.w;
        ss += v.x*v.x + v.y*v.y + v.z*v.z + v.w*v.w;
    }
    #pragma unroll
    for (int off = 32; off; off >>= 1) {
        s  += __shfl_down(s,  off);
        ss += __shfl_down(ss, off);
    }
    __shared__ float sh0[8], sh1[8];
    const int wave = threadIdx.x >> 6, lane = threadIdx.x & 63;
    if (lane == 0) { sh0[wave] = s; sh1[wave] = ss; }
    __syncthreads();
    if (threadIdx.x == 0) {
        float S = 0.f, SS = 0.f;
        const int nw = blockDim.x >> 6;
        for (int w = 0; w < nw; ++w) { S += sh0[w]; SS += sh1[w]; }
        part[(g * GN_SPLIT + sp) * 2]     = S;
        part[(g * GN_SPLIT + sp) * 2 + 1] = SS;
    }
}

// -------------------- 2. Fold GN into QKV weights + w_out fp16 + x transpose ----
__global__ __launch_bounds__(256)
void fold_qkv(const float* __restrict__ w, const float* __restrict__ b,
              const float* __restrict__ gamma, const float* __restrict__ beta,
              const float* __restrict__ part, const float* __restrict__ w_out,
              const float* __restrict__ x,
              _Float16* __restrict__ w2h, float* __restrict__ b2,
              _Float16* __restrict__ wouth, _Float16* __restrict__ xT) {
    const int o = blockIdx.x;
    const int c = threadIdx.x;          // 0..255
    if (o >= 4 * CCH) {                 // ---- transpose tile ----
        const int t  = o - 4 * CCH;     // 0..255
        const int jb = (t & 63) * 64;
        const int cb = (t >> 6) * 64;
        __shared__ float tile[64][65];
        const int tj = threadIdx.x & 63, tc = threadIdx.x >> 6;
        #pragma unroll
        for (int cc = 0; cc < 64; cc += 4)
            tile[cc + tc][tj] = x[(size_t)(cb + cc + tc) * NTOK + jb + tj];
        __syncthreads();
        const int wc = threadIdx.x & 63, wj = threadIdx.x >> 6;
        #pragma unroll
        for (int jj = 0; jj < 64; jj += 4)
            xT[(size_t)(jb + jj + wj) * CCH + cb + wc] = (_Float16)tile[wc][jj + wj];
        return;
    }
    if (o >= 3 * CCH) {                 // ---- w_out convert ----
        const int oo = o - 3 * CCH;
        wouth[(size_t)oo * CCH + c] = (_Float16)w_out[(size_t)oo * CCH + c];
        return;
    }
    __shared__ float smean[GROUPS], srstd[GROUPS];
    if (c < GROUPS) {
        float s = 0.f, ss = 0.f;
        #pragma unroll
        for (int i = 0; i < GN_SPLIT; ++i) {
            s  += part[(c * GN_SPLIT + i) * 2];
            ss += part[(c * GN_SPLIT + i) * 2 + 1];
        }
        const float M = (float)((CCH / GROUPS) * NTOK);
        const float mean = s / M;
        const float var  = ss / M - mean * mean;
        smean[c] = mean;
        srstd[c] = rsqrtf(var + EPS);
    }
    __syncthreads();
    const int g = c >> 5;
    const float sc = gamma[c] * srstd[g];
    const float sh = beta[c] - smean[g] * sc;
    const float wv = w[(size_t)o * CCH + c];
    w2h[(size_t)o * CCH + c] = (_Float16)(wv * sc);
    float t = wv * sh;
    #pragma unroll
    for (int off = 32; off; off >>= 1) t += __shfl_down(t, off);
    __shared__ float shred[4];
    const int wave = threadIdx.x >> 6, lane = threadIdx.x & 63;
    if (lane == 0) shred[wave] = t;
    __syncthreads();
    if (threadIdx.x == 0)
        b2[o] = b[o] + shred[0] + shred[1] + shred[2] + shred[3];
}

// -------------------- 3. QKV GEMM via MFMA, 32 outputs/wave --------------------
__global__ __launch_bounds__(256)
void qkv_mfma(const _Float16* __restrict__ w2h, const float* __restrict__ b2,
              const _Float16* __restrict__ xT,
              _Float16* __restrict__ q_h, _Float16* __restrict__ k_h,
              _Float16* __restrict__ vT_h) {
    const int tid = threadIdx.x, w = tid >> 6, lane = tid & 63;
    const int la = lane & 15, lg = lane >> 4;
    const int jb = blockIdx.x * 64 + w * 16;   // wave's 16 tokens
    const int ob = blockIdx.y * 32;            // 32 output rows (32-aligned: same part/h)
    const int part = ob >> 8;
    f32x4 acc0 = {0.f, 0.f, 0.f, 0.f};
    f32x4 acc1 = {0.f, 0.f, 0.f, 0.f};
    if (part < 2) {
        // A = xT token rows (D row = j), B = w2h o-rows (D col = o)
        const _Float16* arow  = xT  + (size_t)(jb + la) * CCH;
        const _Float16* brow0 = w2h + (size_t)(ob + la) * CCH;
        const _Float16* brow1 = w2h + (size_t)(ob + 16 + la) * CCH;
        #pragma unroll
        for (int kk = 0; kk < CCH; kk += 32) {
            const half8 a  = *(const half8*)(arow  + kk + lg * 8);
            const half8 b0 = *(const half8*)(brow0 + kk + lg * 8);
            const half8 b1 = *(const half8*)(brow1 + kk + lg * 8);
            acc0 = __builtin_amdgcn_mfma_f32_16x16x32_f16(a, b0, acc0, 0, 0, 0);
            acc1 = __builtin_amdgcn_mfma_f32_16x16x32_f16(a, b1, acc1, 0, 0, 0);
        }
        const int h = (ob & 255) >> 5;
        const float bias0 = b2[ob + la];
        const float bias1 = b2[ob + 16 + la];
        _Float16* dst = (part == 0) ? q_h : k_h;
        const float scl = (part == 0) ? 0.17677669529663687f : 1.0f;  // 32^-0.5
        #pragma unroll
        for (int r = 0; r < 4; ++r) {
            const int j = jb + lg * 4 + r;
            _Float16* base = dst + ((size_t)h * NTOK + j) * DIM_HEAD;
            base[la]      = (_Float16)((acc0[r] + bias0) * scl);
            base[16 + la] = (_Float16)((acc1[r] + bias1) * scl);
        }
    } else {
        // A = w2h o-rows (D row = o=d), B = xT token rows (D col = j)
        const _Float16* arow0 = w2h + (size_t)(ob + la) * CCH;
        const _Float16* arow1 = w2h + (size_t)(ob + 16 + la) * CCH;
        const _Float16* brow  = xT  + (size_t)(jb + la) * CCH;
        #pragma unroll
        for (int kk = 0; kk < CCH; kk += 32) {
            const half8 a0 = *(const half8*)(arow0 + kk + lg * 8);
            const half8 a1 = *(const half8*)(arow1 + kk + lg * 8);
            const half8 b  = *(const half8*)(brow  + kk + lg * 8);
            acc0 = __builtin_amdgcn_mfma_f32_16x16x32_f16(a0, b, acc0, 0, 0, 0);
            acc1 = __builtin_amdgcn_mfma_f32_16x16x32_f16(a1, b, acc1, 0, 0, 0);
        }
        const int h = (ob & 255) >> 5;
        const float4 b40 = *(const float4*)(b2 + ob + lg * 4);
        const float4 b41 = *(const float4*)(b2 + ob + 16 + lg * 4);
        const float bb0[4] = {b40.x, b40.y, b40.z, b40.w};
        const float bb1[4] = {b41.x, b41.y, b41.z, b41.w};
        #pragma unroll
        for (int r = 0; r < 4; ++r) {
            const int d0 = lg * 4 + r;
            vT_h[((size_t)h * DIM_HEAD + d0     ) * NTOK + jb + la] = (_Float16)(acc0[r] + bb0[r]);
            vT_h[((size_t)h * DIM_HEAD + d0 + 16) * NTOK + jb + la] = (_Float16)(acc1[r] + bb1[r]);
        }
    }
}

// -------------------- 4. Flash attention: 32x32 MFMA, P in registers (T12) -----
#define TJ 64
#define KPAD 36
#define VPAD 72
__global__ __launch_bounds__(512)
void attn_mfma(const _Float16* __restrict__ q_h, const _Float16* __restrict__ k_h,
               const _Float16* __restrict__ vT_h,
               float* __restrict__ pm, float* __restrict__ pl,
               _Float16* __restrict__ pacc) {
    const int tid = threadIdx.x;                 // 0..511
    const int w = tid >> 6, lane = tid & 63;
    const int la32 = lane & 31, hi = lane >> 5;
    const int h = blockIdx.y;
    const int s = blockIdx.z;
    const int qbase = blockIdx.x * 256 + w * 32;
    const int jlen = NTOK / JS;          // 1024
    const int j0 = s * jlen;

    __shared__ _Float16 lk [2][TJ * KPAD];           // 2 x 4.5 KB (64 key rows)
    __shared__ _Float16 lvt[2][DIM_HEAD * VPAD];     // 2 x 4.5 KB (32 d rows)

    // Q B-fragments: lane holds Q row q=la32, d = c16*16 + hi*8 .. +7
    const _Float16* qrow = q_h + ((size_t)h * NTOK + qbase + la32) * DIM_HEAD;
    const half8 bq0 = *(const half8*)(qrow + hi * 8);
    const half8 bq1 = *(const half8*)(qrow + 16 + hi * 8);

    f32x16 acc;
    #pragma unroll
    for (int r = 0; r < 16; ++r) acc[r] = 0.f;
    float m = -1e30f, l = 0.f;           // per-lane: query la32 (replicated in hi)

    const _Float16* kg_ = k_h  + (size_t)h * NTOK * DIM_HEAD + (size_t)j0 * DIM_HEAD;
    const _Float16* vg  = vT_h + (size_t)h * DIM_HEAD * NTOK + j0;
    const int krow = tid >> 3, kc8 = tid & 7;       // K staging (64 rows x 8B)
    const int vrow = tid >> 4, vseg = tid & 15;     // V^T staging (32 rows x 8B)

    uint2 kreg, vreg;
    kreg = ((const uint2*)kg_)[tid];
    vreg = *(const uint2*)(vg + (size_t)vrow * NTOK + vseg * 4);
    *(uint2*)&lk[0][krow * KPAD + kc8 * 4] = kreg;
    *(uint2*)&lvt[0][vrow * VPAD + vseg * 4] = vreg;
    kreg = ((const uint2*)(kg_ + (size_t)TJ * DIM_HEAD))[tid];
    vreg = *(const uint2*)(vg + (size_t)vrow * NTOK + TJ + vseg * 4);
    __syncthreads();

    const int NT = jlen / TJ;     // 16
    for (int t = 0; t < NT; ++t) {
        const int cur = t & 1;
        if (t + 1 < NT) {
            *(uint2*)&lk[cur ^ 1][krow * KPAD + kc8 * 4] = kreg;
            *(uint2*)&lvt[cur ^ 1][vrow * VPAD + vseg * 4] = vreg;
            if (t + 2 < NT) {
                kreg = ((const uint2*)(kg_ + (size_t)(t + 2) * TJ * DIM_HEAD))[tid];
                vreg = *(const uint2*)(vg + (size_t)vrow * NTOK + (t + 2) * TJ + vseg * 4);
            }
        }
        // ---- QK^T swapped (32x32): sc D[key_local][q=la32] ----
        f32x16 z;
        #pragma unroll
        for (int r = 0; r < 16; ++r) z[r] = 0.f;
        const half8 ak00 = *(const half8*)&lk[cur][(la32     ) * KPAD +      hi * 8];
        const half8 ak01 = *(const half8*)&lk[cur][(la32     ) * KPAD + 16 + hi * 8];
        const half8 ak10 = *(const half8*)&lk[cur][(32 + la32) * KPAD +      hi * 8];
        const half8 ak11 = *(const half8*)&lk[cur][(32 + la32) * KPAD + 16 + hi * 8];
        f32x16 sc0 = __builtin_amdgcn_mfma_f32_32x32x16_f16(ak00, bq0, z, 0, 0, 0);
        sc0        = __builtin_amdgcn_mfma_f32_32x32x16_f16(ak01, bq1, sc0, 0, 0, 0);
        f32x16 sc1 = __builtin_amdgcn_mfma_f32_32x32x16_f16(ak10, bq0, z, 0, 0, 0);
        sc1        = __builtin_amdgcn_mfma_f32_32x32x16_f16(ak11, bq1, sc1, 0, 0, 0);
        // ---- max over 32 in-lane regs + 1 cross-replica shfl ----
        float tm = sc0[0];
        #pragma unroll
        for (int r = 1; r < 16; ++r) tm = fmaxf(tm, sc0[r]);
        #pragma unroll
        for (int r = 0; r < 16; ++r) tm = fmaxf(tm, sc1[r]);
        tm = fmaxf(tm, __shfl_xor(tm, 32));
        const float mn   = fmaxf(m, tm);
        const float corr = __expf(m - mn);
        m = mn;
        l *= corr;
        #pragma unroll
        for (int r = 0; r < 16; ++r) acc[r] *= corr;
        // ---- probabilities (stay in registers) ----
        float p0[16], p1[16];
        float ps = 0.f;
        #pragma unroll
        for (int r = 0; r < 16; ++r) { p0[r] = __expf(sc0[r] - mn); ps += p0[r]; }
        #pragma unroll
        for (int r = 0; r < 16; ++r) { p1[r] = __expf(sc1[r] - mn); ps += p1[r]; }
        l += ps;
        // ---- PV: per 16-key chunk, build P B-frag in-register and MFMA --------
        #define DO_CHUNK(P, C2, CIDX)                                              \
        {                                                                          \
            union { fp16x2 hh; unsigned u; } A_, B_, C_, D_;                       \
            A_.hh = __builtin_amdgcn_cvt_pkrtz(P[8*(C2)+0], P[8*(C2)+1]);          \
            B_.hh = __builtin_amdgcn_cvt_pkrtz(P[8*(C2)+2], P[8*(C2)+3]);          \
            C_.hh = __builtin_amdgcn_cvt_pkrtz(P[8*(C2)+4], P[8*(C2)+5]);          \
            D_.hh = __builtin_amdgcn_cvt_pkrtz(P[8*(C2)+6], P[8*(C2)+7]);          \
            asm("v_permlane32_swap_b32 %0, %1" : "+v"(A_.u), "+v"(C_.u));          \
            asm("v_permlane32_swap_b32 %0, %1" : "+v"(B_.u), "+v"(D_.u));          \
            union { unsigned u[4]; half8 v; } F_;                                  \
            F_.u[0] = A_.u; F_.u[1] = B_.u; F_.u[2] = C_.u; F_.u[3] = D_.u;        \
            const half8 av = *(const half8*)&lvt[cur][la32 * VPAD + (CIDX) * 16 + hi * 8]; \
            acc = __builtin_amdgcn_mfma_f32_32x32x16_f16(av, F_.v, acc, 0, 0, 0);  \
        }
        DO_CHUNK(p0, 0, 0)
        DO_CHUNK(p0, 1, 1)
        DO_CHUNK(p1, 0, 2)
        DO_CHUNK(p1, 1, 3)
        #undef DO_CHUNK
        __syncthreads();
    }
    // ---- epilogue: combine replicas' l; store partial state ----
    float lt = l + __shfl_xor(l, 32);
    const size_t pbase = (size_t)(h * JS + s) * NTOK + qbase;
    if (hi == 0) {
        pm[pbase + la32] = m;
        pl[pbase + la32] = lt;
    }
    // acc[reg] holds out[d = (reg&3)+8*(reg>>2)+4*hi][q = la32]
    #pragma unroll
    for (int g = 0; g < 4; ++g) {
        union { fp16x2 hh; unsigned u; } u0, u1;
        u0.hh = __builtin_amdgcn_cvt_pkrtz(acc[4*g],     acc[4*g + 1]);
        u1.hh = __builtin_amdgcn_cvt_pkrtz(acc[4*g + 2], acc[4*g + 3]);
        uint2 st; st.x = u0.u; st.y = u1.u;
        *(uint2*)(pacc + (pbase + la32) * DIM_HEAD + 8 * g + 4 * hi) = st;
    }
}

// -------------------- 5. Combine partials (JS=4, fp16 pacc) -> attT fp16 -------
__global__ void attn_combine(const float* __restrict__ pm, const float* __restrict__ pl,
                             const _Float16* __restrict__ pacc, _Float16* __restrict__ attT) {
    const int i = blockIdx.x * blockDim.x + threadIdx.x;   // 0..4095
    const int h = blockIdx.y;
    float mv[JS], lv[JS];
    float mM = -1e30f;
    #pragma unroll
    for (int s = 0; s < JS; ++s) {
        const size_t pidx = ((size_t)(h * JS + s) * NTOK + i);
        mv[s] = pm[pidx];
        lv[s] = pl[pidx];
        mM = fmaxf(mM, mv[s]);
    }
    float wv[JS];
    float denom = 0.f;
    #pragma unroll
    for (int s = 0; s < JS; ++s) {
        wv[s] = __expf(mv[s] - mM);
        denom += lv[s] * wv[s];
    }
    const float inv = 1.f / denom;
    __attribute__((aligned(16))) _Float16 hv[DIM_HEAD];
    #pragma unroll
    for (int d0 = 0; d0 < DIM_HEAD; d0 += 4) {
        float o0 = 0.f, o1 = 0.f, o2 = 0.f, o3 = 0.f;
        #pragma unroll
        for (int s = 0; s < JS; ++s) {
            const size_t pidx = ((size_t)(h * JS + s) * NTOK + i);
            const half4 a = *(const half4*)(pacc + pidx * DIM_HEAD + d0);
            o0 = fmaf((float)a.x, wv[s], o0);
            o1 = fmaf((float)a.y, wv[s], o1);
            o2 = fmaf((float)a.z, wv[s], o2);
            o3 = fmaf((float)a.w, wv[s], o3);
        }
        hv[d0]     = (_Float16)(o0 * inv);
        hv[d0 + 1] = (_Float16)(o1 * inv);
        hv[d0 + 2] = (_Float16)(o2 * inv);
        hv[d0 + 3] = (_Float16)(o3 * inv);
    }
    _Float16* dst = attT + (size_t)i * CCH + h * DIM_HEAD;   // 64 B contiguous
    #pragma unroll
    for (int q = 0; q < 4; ++q) ((uint4*)dst)[q] = ((const uint4*)hv)[q];
}

// -------------------- 6. Output projection via MFMA, 32 outputs/wave -----------
__global__ __launch_bounds__(256)
void out_mfma(const _Float16* __restrict__ wouth, const float* __restrict__ bo,
              const _Float16* __restrict__ attT, const float* __restrict__ x,
              float* __restrict__ out) {
    const int tid = threadIdx.x, w = tid >> 6, lane = tid & 63;
    const int la = lane & 15, lg = lane >> 4;
    const int jb = blockIdx.x * 64 + w * 16;
    const int ob = blockIdx.y * 32;
    const _Float16* arow0 = wouth + (size_t)(ob + la) * CCH;        // D row = o
    const _Float16* arow1 = wouth + (size_t)(ob + 16 + la) * CCH;
    const _Float16* brow  = attT  + (size_t)(jb + la) * CCH;        // D col = j
    f32x4 acc0 = {0.f, 0.f, 0.f, 0.f};
    f32x4 acc1 = {0.f, 0.f, 0.f, 0.f};
    #pragma unroll
    for (int kk = 0; kk < CCH; kk += 32) {
        const half8 a0 = *(const half8*)(arow0 + kk + lg * 8);
        const half8 a1 = *(const half8*)(arow1 + kk + lg * 8);
        const half8 b  = *(const half8*)(brow  + kk + lg * 8);
        acc0 = __builtin_amdgcn_mfma_f32_16x16x32_f16(a0, b, acc0, 0, 0, 0);
        acc1 = __builtin_amdgcn_mfma_f32_16x16x32_f16(a1, b, acc1, 0, 0, 0);
    }
    const float4 b40 = *(const float4*)(bo + ob + lg * 4);
    const float4 b41 = *(const float4*)(bo + ob + 16 + lg * 4);
    const float bb0[4] = {b40.x, b40.y, b40.z, b40.w};
    const float bb1[4] = {b41.x, b41.y, b41.z, b41.w};
    #pragma unroll
    for (int r = 0; r < 4; ++r) {
        const int o0 = ob + lg * 4 + r;
        const size_t idx0 = (size_t)o0 * NTOK + jb + la;
        out[idx0] = acc0[r] + bb0[r] + x[idx0];
        const int o1 = ob + 16 + lg * 4 + r;
        const size_t idx1 = (size_t)o1 * NTOK + jb + la;
        out[idx1] = acc1[r] + bb1[r] + x[idx1];
    }
}

extern "C" void kernel_launch(void* const* d_in, const int* in_sizes, int n_in,
                              void* d_out, int out_size, void* d_ws, size_t ws_size,
                              hipStream_t stream) {
    const float* x     = (const float*)d_in[0];
    const float* gamma = (const float*)d_in[1];
    const float* beta  = (const float*)d_in[2];
    const float* w_qkv = (const float*)d_in[3];
    const float* b_qkv = (const float*)d_in[4];
    const float* w_out = (const float*)d_in[5];
    const float* b_out = (const float*)d_in[6];
    float* out = (float*)d_out;

    float* ws   = (float*)d_ws;
    float* part = ws;                           // 512
    float* b2   = part + 512;                   // 768
    float* pm   = b2 + 768;                     // 8*4*4096 = 131072
    float* pl   = pm + 131072;                  // 131072
    _Float16* pacc = (_Float16*)(pl + 131072);  // 8*4*4096*32 halves (8.4 MB)
    float* fend = pl + 131072 + 2097152;        // pacc = 2097152 floats worth
    _Float16* q_h   = (_Float16*)fend;          // 1048576 halves each
    _Float16* k_h   = q_h  + 1048576;
    _Float16* vT_h  = k_h  + 1048576;
    _Float16* xT    = vT_h + 1048576;           // 1048576
    _Float16* w2h   = xT   + 1048576;           // 196608
    _Float16* wouth = w2h  + 196608;            // 65536
    _Float16* attT  = wouth + 65536;            // 1048576
    // total ~23 MB (ws proven >= 92 MB in round 2)

    {
        dim3 g(GN_SPLIT, GROUPS);
        gn_stats_partial<<<g, 256, 0, stream>>>(x, part);
    }
    fold_qkv<<<5 * CCH, 256, 0, stream>>>(w_qkv, b_qkv, gamma, beta, part, w_out, x,
                                          w2h, b2, wouth, xT);
    {
        dim3 g(NTOK / 64, 3 * CCH / 32);
        qkv_mfma<<<g, 256, 0, stream>>>(w2h, b2, xT, q_h, k_h, vT_h);
    }
    {
        dim3 g(NTOK / 256, HEADS, JS);
        attn_mfma<<<g, 512, 0, stream>>>(q_h, k_h, vT_h, pm, pl, pacc);
    }
    {
        dim3 g(NTOK / 256, HEADS);
        attn_combine<<<g, 256, 0, stream>>>(pm, pl, pacc, attT);
    }
    {
        dim3 g(NTOK / 64, CCH / 32);
        out_mfma<<<g, 256, 0, stream>>>(wouth, b_out, attT, x, out);
    }
}